// Round 1
// baseline (1636.144 us; speedup 1.0000x reference)
//
#include <hip/hip_runtime.h>

typedef unsigned short u16;
typedef float f32x4 __attribute__((ext_vector_type(4)));
typedef __bf16 bf16x8 __attribute__((ext_vector_type(8)));
typedef u16 u16x8 __attribute__((ext_vector_type(8)));
typedef u16 u16x4 __attribute__((ext_vector_type(4)));

#define NEG32 (-1e32f)

__device__ __forceinline__ u16 f2bf(float f) {
  union { float f; unsigned u; } v; v.f = f;
  unsigned r = (v.u + 0x7FFFu + ((v.u >> 16) & 1u)) >> 16;
  return (u16)r;
}

__device__ __forceinline__ float wred_max(float v) {
#pragma unroll
  for (int o = 32; o >= 1; o >>= 1) v = fmaxf(v, __shfl_xor(v, o));
  return v;
}
__device__ __forceinline__ float wred_sum(float v) {
#pragma unroll
  for (int o = 32; o >= 1; o >>= 1) v += __shfl_xor(v, o);
  return v;
}
__device__ __forceinline__ float wscan_incl(float v, int lane) {
#pragma unroll
  for (int o = 1; o < 64; o <<= 1) {
    float t = __shfl_up(v, o);
    if (lane >= o) v += t;
  }
  return v;
}

// ---------------------------------------------------------------------------
// bf16 MFMA GEMM: C[M,N] = A[M,K] @ Bt[N,K]^T + bias, optional relu,
// optional f32 / bf16 outputs. 64x64 tile, BK=64, 4 waves (each 32x32).
// ---------------------------------------------------------------------------
template <int RELU, int WF32, int WBF>
__global__ __launch_bounds__(256) void gemm_kernel(
    const u16* __restrict__ A, const u16* __restrict__ Bt,
    const float* __restrict__ bias, float* __restrict__ C,
    u16* __restrict__ Cbf, int M, int N, int K) {
  __shared__ u16 As[64 * 64];
  __shared__ u16 Bs[64 * 64];
  const int tid = threadIdx.x;
  const int lane = tid & 63;
  const int w = tid >> 6;
  const int m0 = blockIdx.x * 64;
  const int n0 = blockIdx.y * 64;
  const int wr = (w >> 1) * 32;
  const int wc = (w & 1) * 32;
  const int l15 = lane & 15, hi = lane >> 4;

  f32x4 acc[2][2] = {};

  for (int k0 = 0; k0 < K; k0 += 64) {
#pragma unroll
    for (int rep = 0; rep < 2; ++rep) {
      int idx = tid + rep * 256;
      int row = idx >> 3, c8 = idx & 7;
      int cs = ((c8 ^ (row & 7)) << 3);  // pre-swizzled source chunk
      __builtin_amdgcn_global_load_lds(
          (const __attribute__((address_space(1))) void*)(A + (size_t)(m0 + row) * K + k0 + cs),
          (__attribute__((address_space(3))) void*)(&As[idx * 8]), 16, 0, 0);
      __builtin_amdgcn_global_load_lds(
          (const __attribute__((address_space(1))) void*)(Bt + (size_t)(n0 + row) * K + k0 + cs),
          (__attribute__((address_space(3))) void*)(&Bs[idx * 8]), 16, 0, 0);
    }
    __syncthreads();
#pragma unroll
    for (int kk = 0; kk < 2; ++kk) {
      int kb = (kk * 32 + (hi << 3)) << 1;  // byte offset within 128B row
      bf16x8 af[2], bfr[2];
#pragma unroll
      for (int mf = 0; mf < 2; ++mf) {
        int m = wr + mf * 16 + l15;
        af[mf] = *(const bf16x8*)((const char*)As + m * 128 + (kb ^ ((m & 7) << 4)));
      }
#pragma unroll
      for (int nf = 0; nf < 2; ++nf) {
        int n = wc + nf * 16 + l15;
        bfr[nf] = *(const bf16x8*)((const char*)Bs + n * 128 + (kb ^ ((n & 7) << 4)));
      }
#pragma unroll
      for (int mf = 0; mf < 2; ++mf)
#pragma unroll
        for (int nf = 0; nf < 2; ++nf)
          acc[mf][nf] = __builtin_amdgcn_mfma_f32_16x16x32_bf16(af[mf], bfr[nf], acc[mf][nf], 0, 0, 0);
    }
    __syncthreads();
  }

#pragma unroll
  for (int mf = 0; mf < 2; ++mf)
#pragma unroll
    for (int nf = 0; nf < 2; ++nf) {
      int col = n0 + wc + nf * 16 + l15;
      float bia = bias[col];
#pragma unroll
      for (int r = 0; r < 4; ++r) {
        int row = m0 + wr + mf * 16 + (hi << 2) + r;
        float val = acc[mf][nf][r] + bia;
        if (RELU) val = fmaxf(val, 0.f);
        if (WF32) C[(size_t)row * N + col] = val;
        if (WBF) Cbf[(size_t)row * N + col] = f2bf(val);
      }
    }
}

// ---------------------------------------------------------------------------
// Distance-decay causal attention. One wave per query row i.
// qk: [8,1024,256] f32 (q == k, kq_same), v: [8,1024,256] f32.
// ao: [8,1024,256] bf16 output (pre-Wo context).
// ---------------------------------------------------------------------------
__global__ __launch_bounds__(256) void attn_kernel(
    const float* __restrict__ qk, const float* __restrict__ vv,
    u16* __restrict__ ao, const float* __restrict__ gam, int excl,
    int zero_pad) {
  __shared__ float kch[128 * 36];   // K chunk, stride 36 (conflict-free b128)
  __shared__ float srow[4][1024];   // score/attn row per wave
  __shared__ float qbuf[4][32];

  const int tid = threadIdx.x, lane = tid & 63, wid = tid >> 6;
  const int i = blockIdx.x * 4 + wid;
  const int b = blockIdx.y >> 3, h = blockIdx.y & 7;
  const float g = -log1pf(__expf(gam[h]));
  const float* kb = qk + (size_t)b * (1024 * 256) + h * 32;
  const float* vb = vv + (size_t)b * (1024 * 256) + h * 32;

  const int nj = excl ? i : (i + 1);
  const int imax = blockIdx.x * 4 + 3;
  const int njmax = excl ? imax : (imax + 1);

  if (lane < 32) qbuf[wid][lane] = kb[(size_t)i * 256 + lane];
#pragma unroll
  for (int blk = 0; blk < 4; ++blk) {
    f32x4 nv = {NEG32, NEG32, NEG32, NEG32};
    *(f32x4*)&srow[wid][blk * 256 + lane * 4] = nv;
  }

  // ---- phase 1: scores into srow ----
  for (int jc = 0; jc < 1024; jc += 128) {
    __syncthreads();
    if (jc < njmax) {
#pragma unroll
      for (int p = 0; p < 4; ++p) {
        int f = p * 256 + tid;
        int r = f >> 3, c4 = f & 7;
        *(float4*)&kch[r * 36 + c4 * 4] =
            *(const float4*)(kb + (size_t)(jc + r) * 256 + c4 * 4);
      }
    }
    __syncthreads();
    if (jc < njmax) {
#pragma unroll
      for (int t = 0; t < 2; ++t) {
        int j = jc + t * 64 + lane;
        float sv = NEG32;
        if (j < nj) {
          const float* kr = &kch[(j - jc) * 36];
          float a = 0.f;
#pragma unroll
          for (int c4 = 0; c4 < 8; ++c4) {
            float4 kvv = *(const float4*)(kr + c4 * 4);
            a += kvv.x * qbuf[wid][c4 * 4 + 0] + kvv.y * qbuf[wid][c4 * 4 + 1] +
                 kvv.z * qbuf[wid][c4 * 4 + 2] + kvv.w * qbuf[wid][c4 * 4 + 3];
          }
          sv = a * 0.17677669529663687f;  // 1/sqrt(32)
        }
        srow[wid][j] = sv;
      }
    }
  }
  __syncthreads();

  // ---- phase 2: softmax -> cumsum decay -> softmax (registers) ----
  // lane owns j = blk*256 + lane*4 + t  (t=0..3, blk=0..3)
  float s[16];
#pragma unroll
  for (int blk = 0; blk < 4; ++blk) {
    float4 sv = *(const float4*)&srow[wid][blk * 256 + lane * 4];
    s[blk * 4 + 0] = sv.x; s[blk * 4 + 1] = sv.y;
    s[blk * 4 + 2] = sv.z; s[blk * 4 + 3] = sv.w;
  }
  float mx = NEG32;
#pragma unroll
  for (int t = 0; t < 16; ++t) mx = fmaxf(mx, s[t]);
  mx = wred_max(mx);
  float e[16];
  float tot = 0.f;
#pragma unroll
  for (int t = 0; t < 16; ++t) { e[t] = __expf(s[t] - mx); tot += e[t]; }
  tot = wred_sum(tot);
  const float inv = 1.f / tot;

  float cum[16];
  float carry = 0.f;
#pragma unroll
  for (int blk = 0; blk < 4; ++blk) {
    int jb = blk * 256 + lane * 4;
    float p0 = (jb + 0 < nj) ? e[blk * 4 + 0] * inv : 0.f;
    float p1 = (jb + 1 < nj) ? e[blk * 4 + 1] * inv : 0.f;
    float p2 = (jb + 2 < nj) ? e[blk * 4 + 2] * inv : 0.f;
    float p3 = (jb + 3 < nj) ? e[blk * 4 + 3] * inv : 0.f;
    float c0 = p0, c1 = c0 + p1, c2 = c1 + p2, c3 = c2 + p3;
    float incl = wscan_incl(c3, lane);
    float ex = incl - c3;
    cum[blk * 4 + 0] = carry + ex + c0;
    cum[blk * 4 + 1] = carry + ex + c1;
    cum[blk * 4 + 2] = carry + ex + c2;
    cum[blk * 4 + 3] = carry + ex + c3;
    carry += __shfl(incl, 63);
  }
  const float totp = carry;

#pragma unroll
  for (int blk = 0; blk < 4; ++blk)
#pragma unroll
    for (int t = 0; t < 4; ++t) {
      int idx = blk * 4 + t;
      int j = blk * 256 + lane * 4 + t;
      if (j < nj) {
        float pos = (float)(i - j);
        float rem = totp - cum[idx];
        float dist = sqrtf(fmaxf(rem * pos, 0.f));
        float te = __expf(dist * g);
        te = fminf(fmaxf(te, 1e-5f), 1e5f);
        s[idx] = s[idx] * te;
      } else {
        s[idx] = NEG32;
      }
    }

  float mx2 = NEG32;
#pragma unroll
  for (int t = 0; t < 16; ++t) mx2 = fmaxf(mx2, s[t]);
  mx2 = wred_max(mx2);
  float tot2 = 0.f;
#pragma unroll
  for (int t = 0; t < 16; ++t) { e[t] = __expf(s[t] - mx2); tot2 += e[t]; }
  tot2 = wred_sum(tot2);
  const float inv2 = 1.f / tot2;
  const bool zp = (zero_pad && i == 0);

#pragma unroll
  for (int blk = 0; blk < 4; ++blk) {
    float4 av;
    av.x = zp ? 0.f : e[blk * 4 + 0] * inv2;
    av.y = zp ? 0.f : e[blk * 4 + 1] * inv2;
    av.z = zp ? 0.f : e[blk * 4 + 2] * inv2;
    av.w = zp ? 0.f : e[blk * 4 + 3] * inv2;
    *(float4*)&srow[wid][blk * 256 + lane * 4] = av;
  }
  __syncthreads();

  // ---- phase 3: PV (global V reads, coalesced per half-wave) ----
  const int d = lane & 31, half = lane >> 5;
  float acc = 0.f;
  {
    int lim = nj - half * 512;
    lim = lim < 0 ? 0 : (lim > 512 ? 512 : lim);
    const float* vrow = vb + (size_t)(half * 512) * 256 + d;
    const float* arow = &srow[wid][half * 512];
#pragma unroll 4
    for (int jj = 0; jj < lim; ++jj) {
      acc += arow[jj] * vrow[(size_t)jj * 256];
    }
  }
  acc += __shfl_xor(acc, 32);
  if (lane < 32) ao[((size_t)b * 1024 + i) * 256 + h * 32 + lane] = f2bf(acc);
}

// ---------------------------------------------------------------------------
// x = LN(res + add) * g + b ; writes f32 and bf16 copies. Wave per 256-row.
// ---------------------------------------------------------------------------
__global__ __launch_bounds__(256) void add_ln_kernel(
    const float* __restrict__ res, const float* __restrict__ add,
    const float* __restrict__ g, const float* __restrict__ b,
    float* __restrict__ outf, u16* __restrict__ outb) {
  const int lane = threadIdx.x & 63, wid = threadIdx.x >> 6;
  const size_t row = (size_t)blockIdx.x * 4 + wid;
  const size_t base = row * 256 + lane * 4;
  float4 rv = *(const float4*)(res + base);
  float4 av = *(const float4*)(add + base);
  float x0 = rv.x + av.x, x1 = rv.y + av.y, x2 = rv.z + av.z, x3 = rv.w + av.w;
  float sm = wred_sum(x0 + x1 + x2 + x3);
  float mu = sm * (1.f / 256.f);
  float d0 = x0 - mu, d1 = x1 - mu, d2 = x2 - mu, d3 = x3 - mu;
  float vs = wred_sum(d0 * d0 + d1 * d1 + d2 * d2 + d3 * d3);
  float rs = rsqrtf(vs * (1.f / 256.f) + 1e-5f);
  float4 gv = *(const float4*)(g + lane * 4);
  float4 bv = *(const float4*)(b + lane * 4);
  float o0 = d0 * rs * gv.x + bv.x;
  float o1 = d1 * rs * gv.y + bv.y;
  float o2 = d2 * rs * gv.z + bv.z;
  float o3 = d3 * rs * gv.w + bv.w;
  float4 ov = {o0, o1, o2, o3};
  *(float4*)(outf + base) = ov;
  u16x4 wv; wv[0] = f2bf(o0); wv[1] = f2bf(o1); wv[2] = f2bf(o2); wv[3] = f2bf(o3);
  *(u16x4*)(outb + base) = wv;
}

__global__ __launch_bounds__(256) void cast_bf_kernel(
    const float* __restrict__ in, u16* __restrict__ out) {
  size_t i = ((size_t)blockIdx.x * 256 + threadIdx.x) * 8;
  float4 a = *(const float4*)(in + i);
  float4 c = *(const float4*)(in + i + 4);
  u16x8 o;
  o[0] = f2bf(a.x); o[1] = f2bf(a.y); o[2] = f2bf(a.z); o[3] = f2bf(a.w);
  o[4] = f2bf(c.x); o[5] = f2bf(c.y); o[6] = f2bf(c.z); o[7] = f2bf(c.w);
  *(u16x8*)(out + i) = o;
}

// Wt[l][n][k] = bf16(W[l][k][n])
__global__ __launch_bounds__(256) void transpose_cast_kernel(
    const float* __restrict__ W, u16* __restrict__ Wt, int K, int N) {
  __shared__ float t[32][33];
  const size_t lo = (size_t)blockIdx.z * K * N;
  int n0 = blockIdx.x * 32, k0 = blockIdx.y * 32;
  int tx = threadIdx.x, ty = threadIdx.y;  // 32 x 8
#pragma unroll
  for (int r = 0; r < 32; r += 8)
    t[ty + r][tx] = W[lo + (size_t)(k0 + ty + r) * N + n0 + tx];
  __syncthreads();
#pragma unroll
  for (int r = 0; r < 32; r += 8)
    Wt[lo + (size_t)(n0 + ty + r) * K + k0 + tx] = f2bf(t[tx][ty + r]);
}

// ---------------------------------------------------------------------------
extern "C" void kernel_launch(void* const* d_in, const int* in_sizes, int n_in,
                              void* d_out, int out_size, void* d_ws,
                              size_t ws_size, hipStream_t stream) {
  const float* q_embed = (const float*)d_in[0];
  const float* qa_embed = (const float*)d_in[1];
  const float* Wk = (const float*)d_in[2];
  const float* bk = (const float*)d_in[3];
  const float* Wv = (const float*)d_in[4];
  const float* bv = (const float*)d_in[5];
  const float* Wo = (const float*)d_in[6];
  const float* bo = (const float*)d_in[7];
  const float* gammas = (const float*)d_in[8];
  const float* ln1_g = (const float*)d_in[9];
  const float* ln1_b = (const float*)d_in[10];
  const float* W1 = (const float*)d_in[11];
  const float* b1 = (const float*)d_in[12];
  const float* W2 = (const float*)d_in[13];
  const float* b2 = (const float*)d_in[14];
  const float* ln2_g = (const float*)d_in[15];
  const float* ln2_b = (const float*)d_in[16];

  const size_t ACT_F32 = (size_t)8192 * 256 * 4;  // 8 MB
  const size_t ACT_BF = (size_t)8192 * 256 * 2;   // 4 MB
  char* p = (char*)d_ws;
  auto carve = [&](size_t bytes) {
    void* r = (void*)p;
    p += (bytes + 255) & ~(size_t)255;
    return r;
  };
  float* yb = (float*)carve(ACT_F32);
  float* xb = (float*)carve(ACT_F32);
  float* qkf = (float*)carve(ACT_F32);
  float* vf = (float*)carve(ACT_F32);
  float* pof = (float*)carve(ACT_F32);
  u16* xbf = (u16*)carve(ACT_BF);
  u16* ybf = (u16*)carve(ACT_BF);
  u16* aobf = (u16*)carve(ACT_BF);
  u16* hbf = (u16*)carve((size_t)8192 * 1024 * 2);  // 16 MB
  u16* Wkt = (u16*)carve((size_t)3 * 65536 * 2);
  u16* Wvt = (u16*)carve((size_t)3 * 65536 * 2);
  u16* Wot = (u16*)carve((size_t)3 * 65536 * 2);
  u16* W1t = (u16*)carve((size_t)3 * 262144 * 2);
  u16* W2t = (u16*)carve((size_t)3 * 262144 * 2);

  dim3 tb(32, 8);
  transpose_cast_kernel<<<dim3(8, 8, 3), tb, 0, stream>>>(Wk, Wkt, 256, 256);
  transpose_cast_kernel<<<dim3(8, 8, 3), tb, 0, stream>>>(Wv, Wvt, 256, 256);
  transpose_cast_kernel<<<dim3(8, 8, 3), tb, 0, stream>>>(Wo, Wot, 256, 256);
  transpose_cast_kernel<<<dim3(32, 8, 3), tb, 0, stream>>>(W1, W1t, 256, 1024);
  transpose_cast_kernel<<<dim3(8, 32, 3), tb, 0, stream>>>(W2, W2t, 1024, 256);
  cast_bf_kernel<<<1024, 256, 0, stream>>>(q_embed, xbf);
  cast_bf_kernel<<<1024, 256, 0, stream>>>(qa_embed, ybf);

  const dim3 gP(128, 4), gF(128, 16);

  // ---- block 0: layer 0, y = qa, incl mask, FFN ----
  gemm_kernel<0, 1, 0><<<gP, 256, 0, stream>>>(ybf, Wkt, bk, qkf, nullptr, 8192, 256, 256);
  gemm_kernel<0, 1, 0><<<gP, 256, 0, stream>>>(ybf, Wvt, bv, vf, nullptr, 8192, 256, 256);
  attn_kernel<<<dim3(256, 64), 256, 0, stream>>>(qkf, vf, aobf, gammas, 0, 0);
  gemm_kernel<0, 1, 0><<<gP, 256, 0, stream>>>(aobf, Wot, bo, pof, nullptr, 8192, 256, 256);
  add_ln_kernel<<<2048, 256, 0, stream>>>(qa_embed, pof, ln1_g, ln1_b, yb, ybf);
  gemm_kernel<1, 0, 1><<<gF, 256, 0, stream>>>(ybf, W1t, b1, nullptr, hbf, 8192, 1024, 256);
  gemm_kernel<0, 1, 0><<<gP, 256, 0, stream>>>(hbf, W2t, b2, pof, nullptr, 8192, 256, 1024);
  add_ln_kernel<<<2048, 256, 0, stream>>>(yb, pof, ln2_g, ln2_b, yb, ybf);

  // ---- block 1: layer 1, x = q_embed, incl mask, no FFN ----
  gemm_kernel<0, 1, 0><<<gP, 256, 0, stream>>>(xbf, Wkt + 65536, bk + 256, qkf, nullptr, 8192, 256, 256);
  gemm_kernel<0, 1, 0><<<gP, 256, 0, stream>>>(xbf, Wvt + 65536, bv + 256, vf, nullptr, 8192, 256, 256);
  attn_kernel<<<dim3(256, 64), 256, 0, stream>>>(qkf, vf, aobf, gammas + 8, 0, 0);
  gemm_kernel<0, 1, 0><<<gP, 256, 0, stream>>>(aobf, Wot + 65536, bo + 256, pof, nullptr, 8192, 256, 256);
  add_ln_kernel<<<2048, 256, 0, stream>>>(q_embed, pof, ln1_g + 256, ln1_b + 256, xb, xbf);

  // ---- block 2: layer 2, q/k from x, v from y, excl mask, zero_pad, FFN ----
  gemm_kernel<0, 1, 0><<<gP, 256, 0, stream>>>(xbf, Wkt + 131072, bk + 512, qkf, nullptr, 8192, 256, 256);
  gemm_kernel<0, 1, 0><<<gP, 256, 0, stream>>>(ybf, Wvt + 131072, bv + 512, vf, nullptr, 8192, 256, 256);
  attn_kernel<<<dim3(256, 64), 256, 0, stream>>>(qkf, vf, aobf, gammas + 16, 1, 1);
  gemm_kernel<0, 1, 0><<<gP, 256, 0, stream>>>(aobf, Wot + 131072, bo + 512, pof, nullptr, 8192, 256, 256);
  add_ln_kernel<<<2048, 256, 0, stream>>>(xb, pof, ln1_g + 512, ln1_b + 512, xb, xbf);
  gemm_kernel<1, 0, 1><<<gF, 256, 0, stream>>>(xbf, W1t + 524288, b1 + 2048, nullptr, hbf, 8192, 1024, 256);
  gemm_kernel<0, 1, 0><<<gP, 256, 0, stream>>>(hbf, W2t + 524288, b2 + 512, pof, nullptr, 8192, 256, 1024);
  add_ln_kernel<<<2048, 256, 0, stream>>>(xb, pof, ln2_g + 512, ln2_b + 512, (float*)d_out, xbf);
}

// Round 2
// 512.960 us; speedup vs baseline: 3.1896x; 3.1896x over previous
//
#include <hip/hip_runtime.h>

typedef unsigned short u16;
typedef float f32x4 __attribute__((ext_vector_type(4)));
typedef __bf16 bf16x8 __attribute__((ext_vector_type(8)));
typedef u16 u16x8 __attribute__((ext_vector_type(8)));
typedef u16 u16x4 __attribute__((ext_vector_type(4)));

__device__ __forceinline__ u16 f2bf(float f) {
  union { float f; unsigned u; } v; v.f = f;
  unsigned r = (v.u + 0x7FFFu + ((v.u >> 16) & 1u)) >> 16;
  return (u16)r;
}
__device__ __forceinline__ unsigned pack2bf(float a, float b) {
  return (unsigned)f2bf(a) | ((unsigned)f2bf(b) << 16);
}
__device__ __forceinline__ float wred_sum(float v) {
#pragma unroll
  for (int o = 32; o >= 1; o >>= 1) v += __shfl_xor(v, o);
  return v;
}

// ---------------------------------------------------------------------------
// bf16 MFMA GEMM: C = A[M,K] @ Bt[N,K]^T + bias. Outputs:
//  WF32: f32 [M][N];  WBF: bf16 [M][N];  WVT: bf16 head-transposed [bh][d][s]
// ---------------------------------------------------------------------------
template <int RELU, int WF32, int WBF, int WVT>
__global__ __launch_bounds__(256) void gemm_kernel(
    const u16* __restrict__ A, const u16* __restrict__ Bt,
    const float* __restrict__ bias, float* __restrict__ C,
    u16* __restrict__ Cbf, int M, int N, int K) {
  __shared__ u16 As[64 * 64];
  __shared__ u16 Bs[64 * 64];
  const int tid = threadIdx.x;
  const int lane = tid & 63;
  const int w = tid >> 6;
  const int m0 = blockIdx.x * 64;
  const int n0 = blockIdx.y * 64;
  const int wr = (w >> 1) * 32;
  const int wc = (w & 1) * 32;
  const int l15 = lane & 15, hi = lane >> 4;

  f32x4 acc[2][2] = {};

  for (int k0 = 0; k0 < K; k0 += 64) {
#pragma unroll
    for (int rep = 0; rep < 2; ++rep) {
      int idx = tid + rep * 256;
      int row = idx >> 3, c8 = idx & 7;
      int cs = ((c8 ^ (row & 7)) << 3);
      __builtin_amdgcn_global_load_lds(
          (const __attribute__((address_space(1))) void*)(A + (size_t)(m0 + row) * K + k0 + cs),
          (__attribute__((address_space(3))) void*)(&As[idx * 8]), 16, 0, 0);
      __builtin_amdgcn_global_load_lds(
          (const __attribute__((address_space(1))) void*)(Bt + (size_t)(n0 + row) * K + k0 + cs),
          (__attribute__((address_space(3))) void*)(&Bs[idx * 8]), 16, 0, 0);
    }
    __syncthreads();
#pragma unroll
    for (int kk = 0; kk < 2; ++kk) {
      int kb = (kk * 32 + (hi << 3)) << 1;
      bf16x8 af[2], bfr[2];
#pragma unroll
      for (int mf = 0; mf < 2; ++mf) {
        int m = wr + mf * 16 + l15;
        af[mf] = *(const bf16x8*)((const char*)As + m * 128 + (kb ^ ((m & 7) << 4)));
      }
#pragma unroll
      for (int nf = 0; nf < 2; ++nf) {
        int n = wc + nf * 16 + l15;
        bfr[nf] = *(const bf16x8*)((const char*)Bs + n * 128 + (kb ^ ((n & 7) << 4)));
      }
#pragma unroll
      for (int mf = 0; mf < 2; ++mf)
#pragma unroll
        for (int nf = 0; nf < 2; ++nf)
          acc[mf][nf] = __builtin_amdgcn_mfma_f32_16x16x32_bf16(af[mf], bfr[nf], acc[mf][nf], 0, 0, 0);
    }
    __syncthreads();
  }

#pragma unroll
  for (int mf = 0; mf < 2; ++mf)
#pragma unroll
    for (int nf = 0; nf < 2; ++nf) {
      int col = n0 + wc + nf * 16 + l15;
      float bia = bias[col];
      u16x4 tv;
#pragma unroll
      for (int r = 0; r < 4; ++r) {
        int row = m0 + wr + mf * 16 + (hi << 2) + r;
        float val = acc[mf][nf][r] + bia;
        if (RELU) val = fmaxf(val, 0.f);
        if (WF32) C[(size_t)row * N + col] = val;
        if (WBF) Cbf[(size_t)row * N + col] = f2bf(val);
        if (WVT) tv[r] = f2bf(val);
      }
      if (WVT) {
        int row0 = m0 + wr + mf * 16 + (hi << 2);
        size_t addr = (((size_t)(row0 >> 10) * 8 + (col >> 5)) * 32 + (col & 31)) * 1024 + (row0 & 1023);
        *(u16x4*)(Cbf + addr) = tv;
      }
    }
}

// ---------------------------------------------------------------------------
// MFMA distance-decay attention. LDS-free; swapped-operand QK^T so the
// per-row cumsum is lane-local (+4-group scan). Two QK^T passes (Z, then
// cumsum/decay/softmax2 + PV). One wave = 16 q rows of one (b,h).
// qkbf: [8192][256] bf16 (q==k projection); vT: [64][32][1024] bf16;
// ao: [8192][256] bf16.
// ---------------------------------------------------------------------------
__global__ __launch_bounds__(256) void attn_mfma_kernel(
    const u16* __restrict__ qkbf, const u16* __restrict__ vT,
    u16* __restrict__ ao, const float* __restrict__ gam, int excl) {
  const int lane = threadIdx.x & 63, w = threadIdx.x >> 6;
  const int qt = blockIdx.x, bh = blockIdx.y;
  const int b = bh >> 3, h = bh & 7;
  const int q0 = qt * 64 + w * 16;
  const int l15 = lane & 15, hi = lane >> 4;
  const int i = q0 + l15;  // this lane's q row
  const float g = -log1pf(__expf(gam[h]));
  const float scale = 0.17677669529663687f;  // 1/sqrt(32)

  const u16* kbase = qkbf + ((size_t)b * 1024) * 256 + h * 32;
  const bf16x8 qfrag = *(const bf16x8*)(kbase + (size_t)(q0 + l15) * 256 + hi * 8);

  const int mylim = i - excl;            // valid k <= mylim
  const int jmax = q0 + 15 - excl;       // wave-wide max valid k
  const int ntiles = (jmax >> 4) + 1;    // >=1 always (q0>=0)

  // ---- pass A: Z (first-softmax denominator; no max-sub, scores are small)
  float zacc = 0.f;
  for (int t = 0; t < ntiles; ++t) {
    bf16x8 kf = *(const bf16x8*)(kbase + (size_t)(t * 16 + l15) * 256 + hi * 8);
    f32x4 sA = {};
    sA = __builtin_amdgcn_mfma_f32_16x16x32_bf16(kf, qfrag, sA, 0, 0, 0);
    const int kb = t * 16 + hi * 4;
#pragma unroll
    for (int r = 0; r < 4; ++r)
      if (kb + r <= mylim) zacc += __expf(sA[r] * scale);
  }
  zacc += __shfl_xor(zacc, 16);
  zacc += __shfl_xor(zacc, 32);
  const float invZ = zacc > 0.f ? 1.f / zacc : 0.f;

  // ---- pass B: cumsum -> decay -> softmax2 -> PV (MFMA) ----
  const u16* vbase = vT + (size_t)bh * 32 * 1024;
  float carry = 0.f, z2 = 0.f;
  f32x4 accO0 = {}, accO1 = {};
  unsigned pk00 = 0, pk01 = 0;
  const int ntB = (ntiles + 1) & ~1;  // pad to even for K=32 PV pairing
  for (int t = 0; t < ntB; ++t) {
    bf16x8 kf = *(const bf16x8*)(kbase + (size_t)(t * 16 + l15) * 256 + hi * 8);
    f32x4 sA = {};
    sA = __builtin_amdgcn_mfma_f32_16x16x32_bf16(kf, qfrag, sA, 0, 0, 0);
    const int kb = t * 16 + hi * 4;
    float sv[4], p[4];
#pragma unroll
    for (int r = 0; r < 4; ++r) {
      sv[r] = sA[r] * scale;
      p[r] = (kb + r <= mylim) ? __expf(sv[r]) * invZ : 0.f;
    }
    // per-row cumsum: in-lane over 4, then scan across the 4 hi groups
    float c1 = p[0] + p[1];
    float c2 = c1 + p[2];
    float c3 = c2 + p[3];
    float vsc = c3;
    float tmp = __shfl_up(vsc, 16); if (hi >= 1) vsc += tmp;
    tmp = __shfl_up(vsc, 32); if (hi >= 2) vsc += tmp;
    const float exg = vsc - c3;   // exclusive over prior hi groups
    const float tot = __shfl(vsc, l15 + 48);
    const float cb = carry + exg;
    float cum[4] = {cb + p[0], cb + c1, cb + c2, cb + c3};
    carry += tot;
    float ep[4];
#pragma unroll
    for (int r = 0; r < 4; ++r) {
      if (kb + r <= mylim) {
        float pos = (float)(i - (kb + r));
        float dist = sqrtf(fmaxf((1.f - cum[r]) * pos, 0.f));
        float te = fmaxf(__expf(dist * g), 1e-5f);
        float e = __expf(sv[r] * te);
        ep[r] = e;
        z2 += e;
      } else {
        ep[r] = 0.f;
      }
    }
    unsigned u0 = pack2bf(ep[0], ep[1]);
    unsigned u1 = pack2bf(ep[2], ep[3]);
    if ((t & 1) == 0) {
      pk00 = u0; pk01 = u1;
    } else {
      // regroup C-layout P^T (k=hi*4+r) into B-frag (k=hi*8..hi*8+7) over 32 k
      const int srcA = l15 + (((2 * hi) & 3) << 4);
      const int srcB = l15 + (((2 * hi + 1) & 3) << 4);
      unsigned a00 = (unsigned)__shfl((int)pk00, srcA);
      unsigned a01 = (unsigned)__shfl((int)u0,   srcA);
      unsigned a10 = (unsigned)__shfl((int)pk01, srcA);
      unsigned a11 = (unsigned)__shfl((int)u1,   srcA);
      unsigned b00 = (unsigned)__shfl((int)pk00, srcB);
      unsigned b01 = (unsigned)__shfl((int)u0,   srcB);
      unsigned b10 = (unsigned)__shfl((int)pk01, srcB);
      unsigned b11 = (unsigned)__shfl((int)u1,   srcB);
      const bool up = hi >= 2;
      union { unsigned u[4]; bf16x8 v; } pf;
      pf.u[0] = up ? a01 : a00;
      pf.u[1] = up ? a11 : a10;
      pf.u[2] = up ? b01 : b00;
      pf.u[3] = up ? b11 : b10;
      const int jb = (t - 1) * 16;
      bf16x8 vf0 = *(const bf16x8*)(vbase + (size_t)l15 * 1024 + jb + hi * 8);
      bf16x8 vf1 = *(const bf16x8*)(vbase + (size_t)(16 + l15) * 1024 + jb + hi * 8);
      accO0 = __builtin_amdgcn_mfma_f32_16x16x32_bf16(vf0, pf.v, accO0, 0, 0, 0);
      accO1 = __builtin_amdgcn_mfma_f32_16x16x32_bf16(vf1, pf.v, accO1, 0, 0, 0);
    }
  }
  z2 += __shfl_xor(z2, 16);
  z2 += __shfl_xor(z2, 32);
  const float inv2 = z2 > 0.f ? 1.f / z2 : 0.f;  // z2==0: excl row 0 (zero_pad)

  u16* aop = ao + ((size_t)(b * 1024 + i)) * 256 + h * 32;
  u16x4 o0, o1;
#pragma unroll
  for (int r = 0; r < 4; ++r) {
    o0[r] = f2bf(accO0[r] * inv2);
    o1[r] = f2bf(accO1[r] * inv2);
  }
  *(u16x4*)(aop + hi * 4) = o0;
  *(u16x4*)(aop + 16 + hi * 4) = o1;
}

// ---------------------------------------------------------------------------
__global__ __launch_bounds__(256) void add_ln_kernel(
    const float* __restrict__ res, const float* __restrict__ add,
    const float* __restrict__ g, const float* __restrict__ b,
    float* __restrict__ outf, u16* __restrict__ outb) {
  const int lane = threadIdx.x & 63, wid = threadIdx.x >> 6;
  const size_t row = (size_t)blockIdx.x * 4 + wid;
  const size_t base = row * 256 + lane * 4;
  float4 rv = *(const float4*)(res + base);
  float4 av = *(const float4*)(add + base);
  float x0 = rv.x + av.x, x1 = rv.y + av.y, x2 = rv.z + av.z, x3 = rv.w + av.w;
  float sm = wred_sum(x0 + x1 + x2 + x3);
  float mu = sm * (1.f / 256.f);
  float d0 = x0 - mu, d1 = x1 - mu, d2 = x2 - mu, d3 = x3 - mu;
  float vs = wred_sum(d0 * d0 + d1 * d1 + d2 * d2 + d3 * d3);
  float rs = rsqrtf(vs * (1.f / 256.f) + 1e-5f);
  float4 gv = *(const float4*)(g + lane * 4);
  float4 bv = *(const float4*)(b + lane * 4);
  float o0 = d0 * rs * gv.x + bv.x;
  float o1 = d1 * rs * gv.y + bv.y;
  float o2 = d2 * rs * gv.z + bv.z;
  float o3 = d3 * rs * gv.w + bv.w;
  float4 ov = {o0, o1, o2, o3};
  *(float4*)(outf + base) = ov;
  u16x4 wv; wv[0] = f2bf(o0); wv[1] = f2bf(o1); wv[2] = f2bf(o2); wv[3] = f2bf(o3);
  *(u16x4*)(outb + base) = wv;
}

__global__ __launch_bounds__(256) void cast_bf_kernel(
    const float* __restrict__ in, u16* __restrict__ out) {
  size_t i = ((size_t)blockIdx.x * 256 + threadIdx.x) * 8;
  float4 a = *(const float4*)(in + i);
  float4 c = *(const float4*)(in + i + 4);
  u16x8 o;
  o[0] = f2bf(a.x); o[1] = f2bf(a.y); o[2] = f2bf(a.z); o[3] = f2bf(a.w);
  o[4] = f2bf(c.x); o[5] = f2bf(c.y); o[6] = f2bf(c.z); o[7] = f2bf(c.w);
  *(u16x8*)(out + i) = o;
}

// Wt[l][n][k] = bf16(W[l][k][n])
__global__ __launch_bounds__(256) void transpose_cast_kernel(
    const float* __restrict__ W, u16* __restrict__ Wt, int K, int N) {
  __shared__ float t[32][33];
  const size_t lo = (size_t)blockIdx.z * K * N;
  int n0 = blockIdx.x * 32, k0 = blockIdx.y * 32;
  int tx = threadIdx.x, ty = threadIdx.y;  // 32 x 8
#pragma unroll
  for (int r = 0; r < 32; r += 8)
    t[ty + r][tx] = W[lo + (size_t)(k0 + ty + r) * N + n0 + tx];
  __syncthreads();
#pragma unroll
  for (int r = 0; r < 32; r += 8)
    Wt[lo + (size_t)(n0 + ty + r) * K + k0 + tx] = f2bf(t[tx][ty + r]);
}

// ---------------------------------------------------------------------------
extern "C" void kernel_launch(void* const* d_in, const int* in_sizes, int n_in,
                              void* d_out, int out_size, void* d_ws,
                              size_t ws_size, hipStream_t stream) {
  const float* q_embed = (const float*)d_in[0];
  const float* qa_embed = (const float*)d_in[1];
  const float* Wk = (const float*)d_in[2];
  const float* bk = (const float*)d_in[3];
  const float* Wv = (const float*)d_in[4];
  const float* bv = (const float*)d_in[5];
  const float* Wo = (const float*)d_in[6];
  const float* bo = (const float*)d_in[7];
  const float* gammas = (const float*)d_in[8];
  const float* ln1_g = (const float*)d_in[9];
  const float* ln1_b = (const float*)d_in[10];
  const float* W1 = (const float*)d_in[11];
  const float* b1 = (const float*)d_in[12];
  const float* W2 = (const float*)d_in[13];
  const float* b2 = (const float*)d_in[14];
  const float* ln2_g = (const float*)d_in[15];
  const float* ln2_b = (const float*)d_in[16];

  const size_t ACT_F32 = (size_t)8192 * 256 * 4;  // 8 MB
  const size_t ACT_BF = (size_t)8192 * 256 * 2;   // 4 MB
  char* p = (char*)d_ws;
  auto carve = [&](size_t bytes) {
    void* r = (void*)p;
    p += (bytes + 255) & ~(size_t)255;
    return r;
  };
  float* yb = (float*)carve(ACT_F32);
  float* xb = (float*)carve(ACT_F32);
  float* pof = (float*)carve(ACT_F32);
  u16* xbf = (u16*)carve(ACT_BF);
  u16* ybf = (u16*)carve(ACT_BF);
  u16* qkbf = (u16*)carve(ACT_BF);
  u16* vTb = (u16*)carve(ACT_BF);
  u16* aobf = (u16*)carve(ACT_BF);
  u16* hbf = (u16*)carve((size_t)8192 * 1024 * 2);  // 16 MB
  u16* Wkt = (u16*)carve((size_t)3 * 65536 * 2);
  u16* Wvt = (u16*)carve((size_t)3 * 65536 * 2);
  u16* Wot = (u16*)carve((size_t)3 * 65536 * 2);
  u16* W1t = (u16*)carve((size_t)3 * 262144 * 2);
  u16* W2t = (u16*)carve((size_t)3 * 262144 * 2);

  dim3 tb(32, 8);
  transpose_cast_kernel<<<dim3(8, 8, 3), tb, 0, stream>>>(Wk, Wkt, 256, 256);
  transpose_cast_kernel<<<dim3(8, 8, 3), tb, 0, stream>>>(Wv, Wvt, 256, 256);
  transpose_cast_kernel<<<dim3(8, 8, 3), tb, 0, stream>>>(Wo, Wot, 256, 256);
  transpose_cast_kernel<<<dim3(32, 8, 3), tb, 0, stream>>>(W1, W1t, 256, 1024);
  transpose_cast_kernel<<<dim3(8, 32, 3), tb, 0, stream>>>(W2, W2t, 1024, 256);
  cast_bf_kernel<<<1024, 256, 0, stream>>>(q_embed, xbf);
  cast_bf_kernel<<<1024, 256, 0, stream>>>(qa_embed, ybf);

  const dim3 gP(128, 4), gF(128, 16);
  const dim3 gA(16, 64);

  // ---- block 0: layer 0, y = qa, incl mask, FFN ----
  gemm_kernel<0, 0, 1, 0><<<gP, 256, 0, stream>>>(ybf, Wkt, bk, nullptr, qkbf, 8192, 256, 256);
  gemm_kernel<0, 0, 0, 1><<<gP, 256, 0, stream>>>(ybf, Wvt, bv, nullptr, vTb, 8192, 256, 256);
  attn_mfma_kernel<<<gA, 256, 0, stream>>>(qkbf, vTb, aobf, gammas, 0);
  gemm_kernel<0, 1, 0, 0><<<gP, 256, 0, stream>>>(aobf, Wot, bo, pof, nullptr, 8192, 256, 256);
  add_ln_kernel<<<2048, 256, 0, stream>>>(qa_embed, pof, ln1_g, ln1_b, yb, ybf);
  gemm_kernel<1, 0, 1, 0><<<gF, 256, 0, stream>>>(ybf, W1t, b1, nullptr, hbf, 8192, 1024, 256);
  gemm_kernel<0, 1, 0, 0><<<gP, 256, 0, stream>>>(hbf, W2t, b2, pof, nullptr, 8192, 256, 1024);
  add_ln_kernel<<<2048, 256, 0, stream>>>(yb, pof, ln2_g, ln2_b, yb, ybf);

  // ---- block 1: layer 1, x = q_embed, incl mask, no FFN ----
  gemm_kernel<0, 0, 1, 0><<<gP, 256, 0, stream>>>(xbf, Wkt + 65536, bk + 256, nullptr, qkbf, 8192, 256, 256);
  gemm_kernel<0, 0, 0, 1><<<gP, 256, 0, stream>>>(xbf, Wvt + 65536, bv + 256, nullptr, vTb, 8192, 256, 256);
  attn_mfma_kernel<<<gA, 256, 0, stream>>>(qkbf, vTb, aobf, gammas + 8, 0);
  gemm_kernel<0, 1, 0, 0><<<gP, 256, 0, stream>>>(aobf, Wot + 65536, bo + 256, pof, nullptr, 8192, 256, 256);
  add_ln_kernel<<<2048, 256, 0, stream>>>(q_embed, pof, ln1_g + 256, ln1_b + 256, xb, xbf);

  // ---- block 2: layer 2, q/k from x, v from y, excl mask (zero_pad natural) ----
  gemm_kernel<0, 0, 1, 0><<<gP, 256, 0, stream>>>(xbf, Wkt + 131072, bk + 512, nullptr, qkbf, 8192, 256, 256);
  gemm_kernel<0, 0, 0, 1><<<gP, 256, 0, stream>>>(ybf, Wvt + 131072, bv + 512, nullptr, vTb, 8192, 256, 256);
  attn_mfma_kernel<<<gA, 256, 0, stream>>>(qkbf, vTb, aobf, gammas + 16, 1);
  gemm_kernel<0, 1, 0, 0><<<gP, 256, 0, stream>>>(aobf, Wot + 131072, bo + 512, pof, nullptr, 8192, 256, 256);
  add_ln_kernel<<<2048, 256, 0, stream>>>(xb, pof, ln1_g + 512, ln1_b + 512, xb, xbf);
  gemm_kernel<1, 0, 1, 0><<<gF, 256, 0, stream>>>(xbf, W1t + 524288, b1 + 2048, nullptr, hbf, 8192, 1024, 256);
  gemm_kernel<0, 1, 0, 0><<<gP, 256, 0, stream>>>(hbf, W2t + 524288, b2 + 512, pof, nullptr, 8192, 256, 1024);
  add_ln_kernel<<<2048, 256, 0, stream>>>(xb, pof, ln2_g + 512, ln2_b + 512, (float*)d_out, xbf);
}

// Round 4
// 325.481 us; speedup vs baseline: 5.0269x; 1.5760x over previous
//
#include <hip/hip_runtime.h>

typedef unsigned short u16;
typedef float f32x4 __attribute__((ext_vector_type(4)));
typedef __bf16 bf16x8 __attribute__((ext_vector_type(8)));
typedef u16 u16x8 __attribute__((ext_vector_type(8)));
typedef u16 u16x4 __attribute__((ext_vector_type(4)));

__device__ __forceinline__ u16 f2bf(float f) {
  union { float f; unsigned u; } v; v.f = f;
  unsigned r = (v.u + 0x7FFFu + ((v.u >> 16) & 1u)) >> 16;
  return (u16)r;
}
__device__ __forceinline__ unsigned pack2bf(float a, float b) {
  return (unsigned)f2bf(a) | ((unsigned)f2bf(b) << 16);
}
__device__ __forceinline__ float wred_sum(float v) {
#pragma unroll
  for (int o = 32; o >= 1; o >>= 1) v += __shfl_xor(v, o);
  return v;
}

// ---------------------------------------------------------------------------
// bf16 MFMA GEMM: C = A[M,K] @ Bt[N,K]^T + bias. Outputs:
//  WF32: f32 [M][N];  WBF: bf16 [M][N];  WVT: bf16 head-transposed [bh][d][s]
// ---------------------------------------------------------------------------
template <int RELU, int WF32, int WBF, int WVT>
__global__ __launch_bounds__(256) void gemm_kernel(
    const u16* __restrict__ A, const u16* __restrict__ Bt,
    const float* __restrict__ bias, float* __restrict__ C,
    u16* __restrict__ Cbf, int M, int N, int K) {
  __shared__ u16 As[64 * 64];
  __shared__ u16 Bs[64 * 64];
  const int tid = threadIdx.x;
  const int lane = tid & 63;
  const int w = tid >> 6;
  const int m0 = blockIdx.x * 64;
  const int n0 = blockIdx.y * 64;
  const int wr = (w >> 1) * 32;
  const int wc = (w & 1) * 32;
  const int l15 = lane & 15, hi = lane >> 4;

  f32x4 acc[2][2] = {};

  for (int k0 = 0; k0 < K; k0 += 64) {
#pragma unroll
    for (int rep = 0; rep < 2; ++rep) {
      int idx = tid + rep * 256;
      int row = idx >> 3, c8 = idx & 7;
      int cs = ((c8 ^ (row & 7)) << 3);
      __builtin_amdgcn_global_load_lds(
          (const __attribute__((address_space(1))) void*)(A + (size_t)(m0 + row) * K + k0 + cs),
          (__attribute__((address_space(3))) void*)(&As[idx * 8]), 16, 0, 0);
      __builtin_amdgcn_global_load_lds(
          (const __attribute__((address_space(1))) void*)(Bt + (size_t)(n0 + row) * K + k0 + cs),
          (__attribute__((address_space(3))) void*)(&Bs[idx * 8]), 16, 0, 0);
    }
    __syncthreads();
#pragma unroll
    for (int kk = 0; kk < 2; ++kk) {
      int kb = (kk * 32 + (hi << 3)) << 1;
      bf16x8 af[2], bfr[2];
#pragma unroll
      for (int mf = 0; mf < 2; ++mf) {
        int m = wr + mf * 16 + l15;
        af[mf] = *(const bf16x8*)((const char*)As + m * 128 + (kb ^ ((m & 7) << 4)));
      }
#pragma unroll
      for (int nf = 0; nf < 2; ++nf) {
        int n = wc + nf * 16 + l15;
        bfr[nf] = *(const bf16x8*)((const char*)Bs + n * 128 + (kb ^ ((n & 7) << 4)));
      }
#pragma unroll
      for (int mf = 0; mf < 2; ++mf)
#pragma unroll
        for (int nf = 0; nf < 2; ++nf)
          acc[mf][nf] = __builtin_amdgcn_mfma_f32_16x16x32_bf16(af[mf], bfr[nf], acc[mf][nf], 0, 0, 0);
    }
    __syncthreads();
  }

#pragma unroll
  for (int mf = 0; mf < 2; ++mf)
#pragma unroll
    for (int nf = 0; nf < 2; ++nf) {
      int col = n0 + wc + nf * 16 + l15;
      float bia = bias[col];
      u16x4 tv;
#pragma unroll
      for (int r = 0; r < 4; ++r) {
        int row = m0 + wr + mf * 16 + (hi << 2) + r;
        float val = acc[mf][nf][r] + bia;
        if (RELU) val = fmaxf(val, 0.f);
        if (WF32) C[(size_t)row * N + col] = val;
        if (WBF) Cbf[(size_t)row * N + col] = f2bf(val);
        if (WVT) tv[r] = f2bf(val);
      }
      if (WVT) {
        int row0 = m0 + wr + mf * 16 + (hi << 2);
        size_t addr = (((size_t)(row0 >> 10) * 8 + (col >> 5)) * 32 + (col & 31)) * 1024 + (row0 & 1023);
        *(u16x4*)(Cbf + addr) = tv;
      }
    }
}

// ---------------------------------------------------------------------------
// Fused K+V projection: A[8192,256] @ WkvT[512,256]^T. Cols 0..255 -> qkbf
// (bf16 row-major, bias bk); cols 256..511 -> vT scatter (bias bv).
// vT must be a valid pointer (V half is always written).
// ---------------------------------------------------------------------------
__global__ __launch_bounds__(256) void gemm_kv_kernel(
    const u16* __restrict__ A, const u16* __restrict__ Bt,
    const float* __restrict__ biasK, const float* __restrict__ biasV,
    u16* __restrict__ qkbf, u16* __restrict__ vT, int M, int N, int K) {
  __shared__ u16 As[64 * 64];
  __shared__ u16 Bs[64 * 64];
  const int tid = threadIdx.x;
  const int lane = tid & 63;
  const int w = tid >> 6;
  const int m0 = blockIdx.x * 64;
  const int n0 = blockIdx.y * 64;
  const int wr = (w >> 1) * 32;
  const int wc = (w & 1) * 32;
  const int l15 = lane & 15, hi = lane >> 4;

  f32x4 acc[2][2] = {};

  for (int k0 = 0; k0 < K; k0 += 64) {
#pragma unroll
    for (int rep = 0; rep < 2; ++rep) {
      int idx = tid + rep * 256;
      int row = idx >> 3, c8 = idx & 7;
      int cs = ((c8 ^ (row & 7)) << 3);
      __builtin_amdgcn_global_load_lds(
          (const __attribute__((address_space(1))) void*)(A + (size_t)(m0 + row) * K + k0 + cs),
          (__attribute__((address_space(3))) void*)(&As[idx * 8]), 16, 0, 0);
      __builtin_amdgcn_global_load_lds(
          (const __attribute__((address_space(1))) void*)(Bt + (size_t)(n0 + row) * K + k0 + cs),
          (__attribute__((address_space(3))) void*)(&Bs[idx * 8]), 16, 0, 0);
    }
    __syncthreads();
#pragma unroll
    for (int kk = 0; kk < 2; ++kk) {
      int kb = (kk * 32 + (hi << 3)) << 1;
      bf16x8 af[2], bfr[2];
#pragma unroll
      for (int mf = 0; mf < 2; ++mf) {
        int m = wr + mf * 16 + l15;
        af[mf] = *(const bf16x8*)((const char*)As + m * 128 + (kb ^ ((m & 7) << 4)));
      }
#pragma unroll
      for (int nf = 0; nf < 2; ++nf) {
        int n = wc + nf * 16 + l15;
        bfr[nf] = *(const bf16x8*)((const char*)Bs + n * 128 + (kb ^ ((n & 7) << 4)));
      }
#pragma unroll
      for (int mf = 0; mf < 2; ++mf)
#pragma unroll
        for (int nf = 0; nf < 2; ++nf)
          acc[mf][nf] = __builtin_amdgcn_mfma_f32_16x16x32_bf16(af[mf], bfr[nf], acc[mf][nf], 0, 0, 0);
    }
    __syncthreads();
  }

  const bool isV = (n0 >= 256);
#pragma unroll
  for (int mf = 0; mf < 2; ++mf)
#pragma unroll
    for (int nf = 0; nf < 2; ++nf) {
      int col = n0 + wc + nf * 16 + l15;
      float bia = isV ? biasV[col - 256] : biasK[col];
      u16x4 tv;
#pragma unroll
      for (int r = 0; r < 4; ++r) {
        int row = m0 + wr + mf * 16 + (hi << 2) + r;
        float val = acc[mf][nf][r] + bia;
        if (!isV) qkbf[(size_t)row * 256 + col] = f2bf(val);
        tv[r] = f2bf(val);
      }
      if (isV) {
        int row0 = m0 + wr + mf * 16 + (hi << 2);
        int vc = col - 256;
        size_t addr = (((size_t)(row0 >> 10) * 8 + (vc >> 5)) * 32 + (vc & 31)) * 1024 + (row0 & 1023);
        *(u16x4*)(vT + addr) = tv;
      }
    }
}

// ---------------------------------------------------------------------------
// MFMA distance-decay attention, k-chunked across the block's 4 waves.
// Block = one 16-row q-tile of one (b,h); wave w owns the w-th contiguous
// quarter of the k-tile range. Two-level cumsum: pass A's per-chunk Z
// partials double as the chunk prefix offsets. PV partials reduced via LDS.
// ---------------------------------------------------------------------------
__global__ __launch_bounds__(256) void attn_mfma_kernel(
    const u16* __restrict__ qkbf, const u16* __restrict__ vT,
    u16* __restrict__ ao, const float* __restrict__ gam, int excl) {
  __shared__ float zbuf[4][16];
  __shared__ float z2buf[4][16];
  __shared__ float accbuf[8][4][64];

  const int lane = threadIdx.x & 63, w = threadIdx.x >> 6;
  const int qt = 63 - blockIdx.y;  // big-work blocks dispatch first
  const int bh = blockIdx.x;
  const int b = bh >> 3, h = bh & 7;
  const int q0 = qt * 16;
  const int l15 = lane & 15, hi = lane >> 4;
  const int i = q0 + l15;  // this lane's q row
  const float g = -log1pf(__expf(gam[h]));
  const float scale = 0.17677669529663687f;  // 1/sqrt(32)

  const u16* kbase = qkbf + ((size_t)b * 1024) * 256 + h * 32;
  const bf16x8 qfrag = *(const bf16x8*)(kbase + (size_t)(q0 + l15) * 256 + hi * 8);

  const int mylim = i - excl;            // valid k <= mylim
  const int jmax = q0 + 15 - excl;       // block-wide max valid k
  const int ntiles = (jmax >> 4) + 1;
  const int C = (ntiles + 3) >> 2;       // tiles per wave chunk
  const int c0 = w * C;
  const int tEnd = (c0 + C < ntiles) ? (c0 + C) : ntiles;
  const int count = (tEnd > c0) ? (tEnd - c0) : 0;

  // ---- pass A: chunk-partial Z (no max-sub; scores are small) ----
  float zacc = 0.f;
  for (int t = c0; t < tEnd; ++t) {
    bf16x8 kf = *(const bf16x8*)(kbase + (size_t)(t * 16 + l15) * 256 + hi * 8);
    f32x4 sA = {};
    sA = __builtin_amdgcn_mfma_f32_16x16x32_bf16(kf, qfrag, sA, 0, 0, 0);
    const int kb = t * 16 + hi * 4;
#pragma unroll
    for (int r = 0; r < 4; ++r)
      if (kb + r <= mylim) zacc += __expf(sA[r] * scale);
  }
  zacc += __shfl_xor(zacc, 16);
  zacc += __shfl_xor(zacc, 32);          // per-row chunk sum, replicated
  if (lane < 16) zbuf[w][lane] = zacc;
  __syncthreads();

  const float zc0 = zbuf[0][l15], zc1 = zbuf[1][l15];
  const float zc2 = zbuf[2][l15], zc3 = zbuf[3][l15];
  const float Z = zc0 + zc1 + zc2 + zc3;
  const float invZ = Z > 0.f ? 1.f / Z : 0.f;
  float prefix = 0.f;
  if (w > 0) prefix += zc0;
  if (w > 1) prefix += zc1;
  if (w > 2) prefix += zc2;

  // ---- pass B: cumsum -> decay -> softmax2 -> PV over this wave's chunk ----
  const u16* vbase = vT + (size_t)bh * 32 * 1024;
  float carry = prefix * invZ, z2 = 0.f;
  f32x4 accO0 = {}, accO1 = {};
  unsigned pk00 = 0, pk01 = 0;
  const int Cp = (count + 1) & ~1;
  for (int tl = 0; tl < Cp; ++tl) {
    const int t = c0 + tl;
    const bool tv = tl < count;  // wave-uniform
    float ep[4] = {0.f, 0.f, 0.f, 0.f};
    if (tv) {
      bf16x8 kf = *(const bf16x8*)(kbase + (size_t)(t * 16 + l15) * 256 + hi * 8);
      f32x4 sA = {};
      sA = __builtin_amdgcn_mfma_f32_16x16x32_bf16(kf, qfrag, sA, 0, 0, 0);
      const int kb = t * 16 + hi * 4;
      float sv[4], p[4];
#pragma unroll
      for (int r = 0; r < 4; ++r) {
        sv[r] = sA[r] * scale;
        p[r] = (kb + r <= mylim) ? __expf(sv[r]) * invZ : 0.f;
      }
      float c1 = p[0] + p[1];
      float c2 = c1 + p[2];
      float c3 = c2 + p[3];
      float vsc = c3;
      float tmp = __shfl_up(vsc, 16); if (hi >= 1) vsc += tmp;
      tmp = __shfl_up(vsc, 32); if (hi >= 2) vsc += tmp;
      const float exg = vsc - c3;
      const float tot = __shfl(vsc, l15 + 48);
      const float cb = carry + exg;
      float cum[4] = {cb + p[0], cb + c1, cb + c2, cb + c3};
      carry += tot;
#pragma unroll
      for (int r = 0; r < 4; ++r) {
        if (kb + r <= mylim) {
          float pos = (float)(i - (kb + r));
          float dist = sqrtf(fmaxf((1.f - cum[r]) * pos, 0.f));
          float te = fmaxf(__expf(dist * g), 1e-5f);
          float e = __expf(sv[r] * te);
          ep[r] = e;
          z2 += e;
        }
      }
    }
    unsigned u0 = pack2bf(ep[0], ep[1]);
    unsigned u1 = pack2bf(ep[2], ep[3]);
    if ((tl & 1) == 0) {
      pk00 = u0; pk01 = u1;
    } else {
      const int srcA = l15 + (((2 * hi) & 3) << 4);
      const int srcB = l15 + (((2 * hi + 1) & 3) << 4);
      unsigned a00 = (unsigned)__shfl((int)pk00, srcA);
      unsigned a01 = (unsigned)__shfl((int)u0,   srcA);
      unsigned a10 = (unsigned)__shfl((int)pk01, srcA);
      unsigned a11 = (unsigned)__shfl((int)u1,   srcA);
      unsigned b00 = (unsigned)__shfl((int)pk00, srcB);
      unsigned b01 = (unsigned)__shfl((int)u0,   srcB);
      unsigned b10 = (unsigned)__shfl((int)pk01, srcB);
      unsigned b11 = (unsigned)__shfl((int)u1,   srcB);
      const bool up = hi >= 2;
      union { unsigned u[4]; bf16x8 v; } pf;
      pf.u[0] = up ? a01 : a00;
      pf.u[1] = up ? a11 : a10;
      pf.u[2] = up ? b01 : b00;
      pf.u[3] = up ? b11 : b10;
      const int jb = (t - 1) * 16;
      bf16x8 vf0 = *(const bf16x8*)(vbase + (size_t)l15 * 1024 + jb + hi * 8);
      bf16x8 vf1 = *(const bf16x8*)(vbase + (size_t)(16 + l15) * 1024 + jb + hi * 8);
      accO0 = __builtin_amdgcn_mfma_f32_16x16x32_bf16(vf0, pf.v, accO0, 0, 0, 0);
      accO1 = __builtin_amdgcn_mfma_f32_16x16x32_bf16(vf1, pf.v, accO1, 0, 0, 0);
    }
  }

  z2 += __shfl_xor(z2, 16);
  z2 += __shfl_xor(z2, 32);
  if (lane < 16) z2buf[w][lane] = z2;
#pragma unroll
  for (int j = 0; j < 4; ++j) {
    accbuf[j][w][lane] = accO0[j];
    accbuf[4 + j][w][lane] = accO1[j];
  }
  __syncthreads();

  if (w == 0) {
    const float z2t = z2buf[0][l15] + z2buf[1][l15] + z2buf[2][l15] + z2buf[3][l15];
    const float inv2 = z2t > 0.f ? 1.f / z2t : 0.f;  // z2t==0: excl row 0 (zero_pad)
    u16* aop = ao + ((size_t)(b * 1024 + i)) * 256 + h * 32;
    u16x4 o0, o1;
#pragma unroll
    for (int j = 0; j < 4; ++j) {
      float s0 = accbuf[j][0][lane] + accbuf[j][1][lane] + accbuf[j][2][lane] + accbuf[j][3][lane];
      float s1 = accbuf[4 + j][0][lane] + accbuf[4 + j][1][lane] + accbuf[4 + j][2][lane] + accbuf[4 + j][3][lane];
      o0[j] = f2bf(s0 * inv2);
      o1[j] = f2bf(s1 * inv2);
    }
    *(u16x4*)(aop + hi * 4) = o0;
    *(u16x4*)(aop + 16 + hi * 4) = o1;
  }
}

// ---------------------------------------------------------------------------
__global__ __launch_bounds__(256) void add_ln_kernel(
    const float* __restrict__ res, const float* __restrict__ add,
    const float* __restrict__ g, const float* __restrict__ b,
    float* __restrict__ outf, u16* __restrict__ outb) {
  const int lane = threadIdx.x & 63, wid = threadIdx.x >> 6;
  const size_t row = (size_t)blockIdx.x * 4 + wid;
  const size_t base = row * 256 + lane * 4;
  float4 rv = *(const float4*)(res + base);
  float4 av = *(const float4*)(add + base);
  float x0 = rv.x + av.x, x1 = rv.y + av.y, x2 = rv.z + av.z, x3 = rv.w + av.w;
  float sm = wred_sum(x0 + x1 + x2 + x3);
  float mu = sm * (1.f / 256.f);
  float d0 = x0 - mu, d1 = x1 - mu, d2 = x2 - mu, d3 = x3 - mu;
  float vs = wred_sum(d0 * d0 + d1 * d1 + d2 * d2 + d3 * d3);
  float rs = rsqrtf(vs * (1.f / 256.f) + 1e-5f);
  float4 gv = *(const float4*)(g + lane * 4);
  float4 bv = *(const float4*)(b + lane * 4);
  float o0 = d0 * rs * gv.x + bv.x;
  float o1 = d1 * rs * gv.y + bv.y;
  float o2 = d2 * rs * gv.z + bv.z;
  float o3 = d3 * rs * gv.w + bv.w;
  float4 ov = {o0, o1, o2, o3};
  *(float4*)(outf + base) = ov;
  u16x4 wv; wv[0] = f2bf(o0); wv[1] = f2bf(o1); wv[2] = f2bf(o2); wv[3] = f2bf(o3);
  *(u16x4*)(outb + base) = wv;
}

__global__ __launch_bounds__(256) void cast_bf_kernel(
    const float* __restrict__ in, u16* __restrict__ out) {
  size_t i = ((size_t)blockIdx.x * 256 + threadIdx.x) * 8;
  float4 a = *(const float4*)(in + i);
  float4 c = *(const float4*)(in + i + 4);
  u16x8 o;
  o[0] = f2bf(a.x); o[1] = f2bf(a.y); o[2] = f2bf(a.z); o[3] = f2bf(a.w);
  o[4] = f2bf(c.x); o[5] = f2bf(c.y); o[6] = f2bf(c.z); o[7] = f2bf(c.w);
  *(u16x8*)(out + i) = o;
}

// Wt[z*dstStride + n*K + k] = bf16(W[z*K*N + k*N + n])
__global__ __launch_bounds__(256) void transpose_cast_kernel(
    const float* __restrict__ W, u16* __restrict__ Wt, int K, int N,
    int dstStride) {
  __shared__ float t[32][33];
  const size_t lo = (size_t)blockIdx.z * K * N;
  const size_t lod = (size_t)blockIdx.z * dstStride;
  int n0 = blockIdx.x * 32, k0 = blockIdx.y * 32;
  int tx = threadIdx.x, ty = threadIdx.y;  // 32 x 8
#pragma unroll
  for (int r = 0; r < 32; r += 8)
    t[ty + r][tx] = W[lo + (size_t)(k0 + ty + r) * N + n0 + tx];
  __syncthreads();
#pragma unroll
  for (int r = 0; r < 32; r += 8)
    Wt[lod + (size_t)(n0 + ty + r) * K + k0 + tx] = f2bf(t[tx][ty + r]);
}

// ---------------------------------------------------------------------------
extern "C" void kernel_launch(void* const* d_in, const int* in_sizes, int n_in,
                              void* d_out, int out_size, void* d_ws,
                              size_t ws_size, hipStream_t stream) {
  const float* q_embed = (const float*)d_in[0];
  const float* qa_embed = (const float*)d_in[1];
  const float* Wk = (const float*)d_in[2];
  const float* bk = (const float*)d_in[3];
  const float* Wv = (const float*)d_in[4];
  const float* bv = (const float*)d_in[5];
  const float* Wo = (const float*)d_in[6];
  const float* bo = (const float*)d_in[7];
  const float* gammas = (const float*)d_in[8];
  const float* ln1_g = (const float*)d_in[9];
  const float* ln1_b = (const float*)d_in[10];
  const float* W1 = (const float*)d_in[11];
  const float* b1 = (const float*)d_in[12];
  const float* W2 = (const float*)d_in[13];
  const float* b2 = (const float*)d_in[14];
  const float* ln2_g = (const float*)d_in[15];
  const float* ln2_b = (const float*)d_in[16];

  const size_t ACT_F32 = (size_t)8192 * 256 * 4;  // 8 MB
  const size_t ACT_BF = (size_t)8192 * 256 * 2;   // 4 MB
  char* p = (char*)d_ws;
  auto carve = [&](size_t bytes) {
    void* r = (void*)p;
    p += (bytes + 255) & ~(size_t)255;
    return r;
  };
  float* yb = (float*)carve(ACT_F32);
  float* xb = (float*)carve(ACT_F32);
  float* pof = (float*)carve(ACT_F32);
  u16* xbf = (u16*)carve(ACT_BF);
  u16* ybf = (u16*)carve(ACT_BF);
  u16* qkbf = (u16*)carve(ACT_BF);
  u16* vTb = (u16*)carve(ACT_BF);
  u16* aobf = (u16*)carve(ACT_BF);
  u16* hbf = (u16*)carve((size_t)8192 * 1024 * 2);  // 16 MB
  u16* Wkvt = (u16*)carve((size_t)3 * 131072 * 2);
  u16* Wot = (u16*)carve((size_t)3 * 65536 * 2);
  u16* W1t = (u16*)carve((size_t)3 * 262144 * 2);
  u16* W2t = (u16*)carve((size_t)3 * 262144 * 2);

  dim3 tb(32, 8);
  transpose_cast_kernel<<<dim3(8, 8, 3), tb, 0, stream>>>(Wk, Wkvt, 256, 256, 131072);
  transpose_cast_kernel<<<dim3(8, 8, 3), tb, 0, stream>>>(Wv, Wkvt + 65536, 256, 256, 131072);
  transpose_cast_kernel<<<dim3(8, 8, 3), tb, 0, stream>>>(Wo, Wot, 256, 256, 65536);
  transpose_cast_kernel<<<dim3(32, 8, 3), tb, 0, stream>>>(W1, W1t, 256, 1024, 262144);
  transpose_cast_kernel<<<dim3(8, 32, 3), tb, 0, stream>>>(W2, W2t, 1024, 256, 262144);
  cast_bf_kernel<<<1024, 256, 0, stream>>>(q_embed, xbf);
  cast_bf_kernel<<<1024, 256, 0, stream>>>(qa_embed, ybf);

  const dim3 gP(128, 4), gF(128, 16), gKV(128, 8);
  const dim3 gA(64, 64);

  // ---- block 0: layer 0, y = qa, incl mask, FFN ----
  gemm_kv_kernel<<<gKV, 256, 0, stream>>>(ybf, Wkvt, bk, bv, qkbf, vTb, 8192, 512, 256);
  attn_mfma_kernel<<<gA, 256, 0, stream>>>(qkbf, vTb, aobf, gammas, 0);
  gemm_kernel<0, 1, 0, 0><<<gP, 256, 0, stream>>>(aobf, Wot, bo, pof, nullptr, 8192, 256, 256);
  add_ln_kernel<<<2048, 256, 0, stream>>>(qa_embed, pof, ln1_g, ln1_b, yb, ybf);
  gemm_kernel<1, 0, 1, 0><<<gF, 256, 0, stream>>>(ybf, W1t, b1, nullptr, hbf, 8192, 1024, 256);
  gemm_kernel<0, 1, 0, 0><<<gP, 256, 0, stream>>>(hbf, W2t, b2, pof, nullptr, 8192, 256, 1024);
  add_ln_kernel<<<2048, 256, 0, stream>>>(yb, pof, ln2_g, ln2_b, yb, ybf);

  // ---- block 1: layer 1, x = q_embed, incl mask, no FFN ----
  gemm_kv_kernel<<<gKV, 256, 0, stream>>>(xbf, Wkvt + 131072, bk + 256, bv + 256, qkbf, vTb, 8192, 512, 256);
  attn_mfma_kernel<<<gA, 256, 0, stream>>>(qkbf, vTb, aobf, gammas + 8, 0);
  gemm_kernel<0, 1, 0, 0><<<gP, 256, 0, stream>>>(aobf, Wot + 65536, bo + 256, pof, nullptr, 8192, 256, 256);
  add_ln_kernel<<<2048, 256, 0, stream>>>(q_embed, pof, ln1_g + 256, ln1_b + 256, xb, xbf);

  // ---- block 2: layer 2, q/k from x, v from y, excl mask (zero_pad natural) ----
  // Fused KV writes V(x) into vTb (garbage), then the V(y) GEMM fully
  // overwrites vTb before attention reads it (same stream => ordered).
  gemm_kv_kernel<<<gKV, 256, 0, stream>>>(xbf, Wkvt + 262144, bk + 512, bv + 512, qkbf, vTb, 8192, 512, 256);
  gemm_kernel<0, 0, 0, 1><<<gP, 256, 0, stream>>>(ybf, Wkvt + 262144 + 65536, bv + 512, nullptr, vTb, 8192, 256, 256);
  attn_mfma_kernel<<<gA, 256, 0, stream>>>(qkbf, vTb, aobf, gammas + 16, 1);
  gemm_kernel<0, 1, 0, 0><<<gP, 256, 0, stream>>>(aobf, Wot + 131072, bo + 512, pof, nullptr, 8192, 256, 256);
  add_ln_kernel<<<2048, 256, 0, stream>>>(xb, pof, ln1_g + 512, ln1_b + 512, xb, xbf);
  gemm_kernel<1, 0, 1, 0><<<gF, 256, 0, stream>>>(xbf, W1t + 524288, b1 + 2048, nullptr, hbf, 8192, 1024, 256);
  gemm_kernel<0, 1, 0, 0><<<gP, 256, 0, stream>>>(hbf, W2t + 524288, b2 + 512, pof, nullptr, 8192, 256, 1024);
  add_ln_kernel<<<2048, 256, 0, stream>>>(xb, pof, ln2_g + 512, ln2_b + 512, (float*)d_out, xbf);
}

// Round 5
// 305.241 us; speedup vs baseline: 5.3602x; 1.0663x over previous
//
#include <hip/hip_runtime.h>

typedef unsigned short u16;
typedef float f32x4 __attribute__((ext_vector_type(4)));
typedef __bf16 bf16x8 __attribute__((ext_vector_type(8)));
typedef u16 u16x8 __attribute__((ext_vector_type(8)));
typedef u16 u16x4 __attribute__((ext_vector_type(4)));

__device__ __forceinline__ u16 f2bf(float f) {
  union { float f; unsigned u; } v; v.f = f;
  unsigned r = (v.u + 0x7FFFu + ((v.u >> 16) & 1u)) >> 16;
  return (u16)r;
}
__device__ __forceinline__ unsigned cvtpk_bf16(float lo, float hi) {
  unsigned r;
  asm("v_cvt_pk_bf16_f32 %0, %1, %2" : "=v"(r) : "v"(lo), "v"(hi));
  return r;
}
__device__ __forceinline__ float wred_sum(float v) {
#pragma unroll
  for (int o = 32; o >= 1; o >>= 1) v += __shfl_xor(v, o);
  return v;
}

// ---------------------------------------------------------------------------
// bf16 MFMA GEMM: C = A[M,K] @ Bt[N,K]^T + bias. Outputs:
//  WF32: f32 [M][N];  WBF: bf16 [M][N];  WVT: bf16 head-transposed [bh][d][s]
// ---------------------------------------------------------------------------
template <int RELU, int WF32, int WBF, int WVT>
__global__ __launch_bounds__(256) void gemm_kernel(
    const u16* __restrict__ A, const u16* __restrict__ Bt,
    const float* __restrict__ bias, float* __restrict__ C,
    u16* __restrict__ Cbf, int M, int N, int K) {
  __shared__ u16 As[64 * 64];
  __shared__ u16 Bs[64 * 64];
  const int tid = threadIdx.x;
  const int lane = tid & 63;
  const int w = tid >> 6;
  const int m0 = blockIdx.x * 64;
  const int n0 = blockIdx.y * 64;
  const int wr = (w >> 1) * 32;
  const int wc = (w & 1) * 32;
  const int l15 = lane & 15, hi = lane >> 4;

  f32x4 acc[2][2] = {};

  for (int k0 = 0; k0 < K; k0 += 64) {
#pragma unroll
    for (int rep = 0; rep < 2; ++rep) {
      int idx = tid + rep * 256;
      int row = idx >> 3, c8 = idx & 7;
      int cs = ((c8 ^ (row & 7)) << 3);
      __builtin_amdgcn_global_load_lds(
          (const __attribute__((address_space(1))) void*)(A + (size_t)(m0 + row) * K + k0 + cs),
          (__attribute__((address_space(3))) void*)(&As[idx * 8]), 16, 0, 0);
      __builtin_amdgcn_global_load_lds(
          (const __attribute__((address_space(1))) void*)(Bt + (size_t)(n0 + row) * K + k0 + cs),
          (__attribute__((address_space(3))) void*)(&Bs[idx * 8]), 16, 0, 0);
    }
    __syncthreads();
#pragma unroll
    for (int kk = 0; kk < 2; ++kk) {
      int kb = (kk * 32 + (hi << 3)) << 1;
      bf16x8 af[2], bfr[2];
#pragma unroll
      for (int mf = 0; mf < 2; ++mf) {
        int m = wr + mf * 16 + l15;
        af[mf] = *(const bf16x8*)((const char*)As + m * 128 + (kb ^ ((m & 7) << 4)));
      }
#pragma unroll
      for (int nf = 0; nf < 2; ++nf) {
        int n = wc + nf * 16 + l15;
        bfr[nf] = *(const bf16x8*)((const char*)Bs + n * 128 + (kb ^ ((n & 7) << 4)));
      }
#pragma unroll
      for (int mf = 0; mf < 2; ++mf)
#pragma unroll
        for (int nf = 0; nf < 2; ++nf)
          acc[mf][nf] = __builtin_amdgcn_mfma_f32_16x16x32_bf16(af[mf], bfr[nf], acc[mf][nf], 0, 0, 0);
    }
    __syncthreads();
  }

#pragma unroll
  for (int mf = 0; mf < 2; ++mf)
#pragma unroll
    for (int nf = 0; nf < 2; ++nf) {
      int col = n0 + wc + nf * 16 + l15;
      float bia = bias[col];
      u16x4 tv;
#pragma unroll
      for (int r = 0; r < 4; ++r) {
        int row = m0 + wr + mf * 16 + (hi << 2) + r;
        float val = acc[mf][nf][r] + bia;
        if (RELU) val = fmaxf(val, 0.f);
        if (WF32) C[(size_t)row * N + col] = val;
        if (WBF) Cbf[(size_t)row * N + col] = f2bf(val);
        if (WVT) tv[r] = f2bf(val);
      }
      if (WVT) {
        int row0 = m0 + wr + mf * 16 + (hi << 2);
        size_t addr = (((size_t)(row0 >> 10) * 8 + (col >> 5)) * 32 + (col & 31)) * 1024 + (row0 & 1023);
        *(u16x4*)(Cbf + addr) = tv;
      }
    }
}

// ---------------------------------------------------------------------------
// Fused K+V projection: A[8192,256] @ WkvT[512,256]^T. Cols 0..255 -> qkbf
// (bf16 row-major, bias bk); cols 256..511 -> vT scatter (bias bv).
// vT must be a valid pointer (V half is always written).
// ---------------------------------------------------------------------------
__global__ __launch_bounds__(256) void gemm_kv_kernel(
    const u16* __restrict__ A, const u16* __restrict__ Bt,
    const float* __restrict__ biasK, const float* __restrict__ biasV,
    u16* __restrict__ qkbf, u16* __restrict__ vT, int M, int N, int K) {
  __shared__ u16 As[64 * 64];
  __shared__ u16 Bs[64 * 64];
  const int tid = threadIdx.x;
  const int lane = tid & 63;
  const int w = tid >> 6;
  const int m0 = blockIdx.x * 64;
  const int n0 = blockIdx.y * 64;
  const int wr = (w >> 1) * 32;
  const int wc = (w & 1) * 32;
  const int l15 = lane & 15, hi = lane >> 4;

  f32x4 acc[2][2] = {};

  for (int k0 = 0; k0 < K; k0 += 64) {
#pragma unroll
    for (int rep = 0; rep < 2; ++rep) {
      int idx = tid + rep * 256;
      int row = idx >> 3, c8 = idx & 7;
      int cs = ((c8 ^ (row & 7)) << 3);
      __builtin_amdgcn_global_load_lds(
          (const __attribute__((address_space(1))) void*)(A + (size_t)(m0 + row) * K + k0 + cs),
          (__attribute__((address_space(3))) void*)(&As[idx * 8]), 16, 0, 0);
      __builtin_amdgcn_global_load_lds(
          (const __attribute__((address_space(1))) void*)(Bt + (size_t)(n0 + row) * K + k0 + cs),
          (__attribute__((address_space(3))) void*)(&Bs[idx * 8]), 16, 0, 0);
    }
    __syncthreads();
#pragma unroll
    for (int kk = 0; kk < 2; ++kk) {
      int kb = (kk * 32 + (hi << 3)) << 1;
      bf16x8 af[2], bfr[2];
#pragma unroll
      for (int mf = 0; mf < 2; ++mf) {
        int m = wr + mf * 16 + l15;
        af[mf] = *(const bf16x8*)((const char*)As + m * 128 + (kb ^ ((m & 7) << 4)));
      }
#pragma unroll
      for (int nf = 0; nf < 2; ++nf) {
        int n = wc + nf * 16 + l15;
        bfr[nf] = *(const bf16x8*)((const char*)Bs + n * 128 + (kb ^ ((n & 7) << 4)));
      }
#pragma unroll
      for (int mf = 0; mf < 2; ++mf)
#pragma unroll
        for (int nf = 0; nf < 2; ++nf)
          acc[mf][nf] = __builtin_amdgcn_mfma_f32_16x16x32_bf16(af[mf], bfr[nf], acc[mf][nf], 0, 0, 0);
    }
    __syncthreads();
  }

  const bool isV = (n0 >= 256);
#pragma unroll
  for (int mf = 0; mf < 2; ++mf)
#pragma unroll
    for (int nf = 0; nf < 2; ++nf) {
      int col = n0 + wc + nf * 16 + l15;
      float bia = isV ? biasV[col - 256] : biasK[col];
      u16x4 tv;
#pragma unroll
      for (int r = 0; r < 4; ++r) {
        int row = m0 + wr + mf * 16 + (hi << 2) + r;
        float val = acc[mf][nf][r] + bia;
        if (!isV) qkbf[(size_t)row * 256 + col] = f2bf(val);
        tv[r] = f2bf(val);
      }
      if (isV) {
        int row0 = m0 + wr + mf * 16 + (hi << 2);
        int vc = col - 256;
        size_t addr = (((size_t)(row0 >> 10) * 8 + (vc >> 5)) * 32 + (vc & 31)) * 1024 + (row0 & 1023);
        *(u16x4*)(vT + addr) = tv;
      }
    }
}

// ---------------------------------------------------------------------------
// MFMA distance-decay attention, k-chunked across the block's 4 waves.
// Interior/diagonal tile split (only tile t==ntiles-1 has masked elements),
// e-domain cumsum (invZ applied post-scan), v_cvt_pk_bf16_f32 packing,
// 1-deep software pipeline on the QK MFMA.
// ---------------------------------------------------------------------------
__global__ __launch_bounds__(256) void attn_mfma_kernel(
    const u16* __restrict__ qkbf, const u16* __restrict__ vT,
    u16* __restrict__ ao, const float* __restrict__ gam, int excl) {
  __shared__ float zbuf[4][16];
  __shared__ float z2buf[4][16];
  __shared__ float accbuf[8][4][64];

  const int lane = threadIdx.x & 63, w = threadIdx.x >> 6;
  const int qt = 63 - blockIdx.y;  // big-work blocks dispatch first
  const int bh = blockIdx.x;
  const int b = bh >> 3, h = bh & 7;
  const int q0 = qt * 16;
  const int l15 = lane & 15, hi = lane >> 4;
  const int i = q0 + l15;  // this lane's q row
  const float g = -log1pf(__expf(gam[h]));
  const float scale = 0.17677669529663687f;  // 1/sqrt(32)

  const u16* kbase = qkbf + ((size_t)b * 1024) * 256 + h * 32;
  const bf16x8 qfrag = *(const bf16x8*)(kbase + (size_t)i * 256 + hi * 8);

  const int mylim = i - excl;            // valid k <= mylim
  const int jmax = q0 + 15 - excl;       // block-wide max valid k
  const int ntiles = (jmax >> 4) + 1;
  const int C = (ntiles + 3) >> 2;       // tiles per wave chunk
  const int c0 = w * C;
  const int tEnd = (c0 + C < ntiles) ? (c0 + C) : ntiles;
  const int count = (tEnd > c0) ? (tEnd - c0) : 0;

  // ---- pass A: chunk-partial Z (e-domain; no max-sub, scores are small) ----
  float zacc = 0.f;
  for (int t = c0; t < tEnd; ++t) {
    bf16x8 kf = *(const bf16x8*)(kbase + (size_t)(t * 16 + l15) * 256 + hi * 8);
    f32x4 sA = {};
    sA = __builtin_amdgcn_mfma_f32_16x16x32_bf16(kf, qfrag, sA, 0, 0, 0);
    if (t == ntiles - 1) {               // wave-uniform: diagonal tile
      const int kb = t * 16 + hi * 4;
#pragma unroll
      for (int r = 0; r < 4; ++r)
        zacc += (kb + r <= mylim) ? __expf(sA[r] * scale) : 0.f;
    } else {
#pragma unroll
      for (int r = 0; r < 4; ++r) zacc += __expf(sA[r] * scale);
    }
  }
  zacc += __shfl_xor(zacc, 16);
  zacc += __shfl_xor(zacc, 32);          // per-row chunk sum, replicated
  if (lane < 16) zbuf[w][lane] = zacc;
  __syncthreads();

  const float zc0 = zbuf[0][l15], zc1 = zbuf[1][l15];
  const float zc2 = zbuf[2][l15], zc3 = zbuf[3][l15];
  const float Z = zc0 + zc1 + zc2 + zc3;
  const float invZ = Z > 0.f ? 1.f / Z : 0.f;
  float prefix = 0.f;
  if (w > 0) prefix += zc0;
  if (w > 1) prefix += zc1;
  if (w > 2) prefix += zc2;

  // ---- pass B: e-domain cumsum -> decay -> softmax2 -> PV ----
  const u16* vbase = vT + (size_t)bh * 32 * 1024;
  float carry = prefix, z2 = 0.f;
  f32x4 accO0 = {}, accO1 = {};
  unsigned pk00 = 0, pk01 = 0;
  const int Cp = (count + 1) & ~1;

  f32x4 sA_cur = {};
  if (count > 0) {
    bf16x8 kf = *(const bf16x8*)(kbase + (size_t)(c0 * 16 + l15) * 256 + hi * 8);
    sA_cur = __builtin_amdgcn_mfma_f32_16x16x32_bf16(kf, qfrag, sA_cur, 0, 0, 0);
  }
  for (int tl = 0; tl < Cp; ++tl) {
    const int t = c0 + tl;
    // pipeline: next tile's QK MFMA is independent of the carry chain
    f32x4 sA_nxt = {};
    if (tl + 1 < count) {
      bf16x8 kf = *(const bf16x8*)(kbase + (size_t)((t + 1) * 16 + l15) * 256 + hi * 8);
      sA_nxt = __builtin_amdgcn_mfma_f32_16x16x32_bf16(kf, qfrag, sA_nxt, 0, 0, 0);
    }
    float ep0 = 0.f, ep1 = 0.f, ep2 = 0.f, ep3 = 0.f;
    if (tl < count) {
      const int kb = t * 16 + hi * 4;
      const bool diag = (t == ntiles - 1);  // wave-uniform
      const float sv0 = sA_cur[0] * scale, sv1 = sA_cur[1] * scale;
      const float sv2 = sA_cur[2] * scale, sv3 = sA_cur[3] * scale;
      float e0 = __expf(sv0), e1 = __expf(sv1);
      float e2 = __expf(sv2), e3 = __expf(sv3);
      bool m0 = true, m1 = true, m2 = true, m3 = true;
      if (diag) {
        m0 = (kb + 0 <= mylim); m1 = (kb + 1 <= mylim);
        m2 = (kb + 2 <= mylim); m3 = (kb + 3 <= mylim);
        e0 = m0 ? e0 : 0.f; e1 = m1 ? e1 : 0.f;
        e2 = m2 ? e2 : 0.f; e3 = m3 ? e3 : 0.f;
      }
      const float cA = e0 + e1, cB = cA + e2, cC = cB + e3;
      float vsc = cC;
      float tmp = __shfl_up(vsc, 16); if (hi >= 1) vsc += tmp;
      tmp = __shfl_up(vsc, 32); if (hi >= 2) vsc += tmp;
      const float exg = vsc - cC;
      const float tot = __shfl(vsc, l15 + 48);
      const float cb = carry + exg;
      carry += tot;
      const float posb = (float)(i - kb);
      const float cum0 = cb + e0, cum1 = cb + cA, cum2 = cb + cB, cum3 = cb + cC;
      const float d20 = fmaxf((Z - cum0) * invZ * posb, 0.f);
      const float d21 = fmaxf((Z - cum1) * invZ * (posb - 1.f), 0.f);
      const float d22 = fmaxf((Z - cum2) * invZ * (posb - 2.f), 0.f);
      const float d23 = fmaxf((Z - cum3) * invZ * (posb - 3.f), 0.f);
      const float te0 = fmaxf(__expf(__builtin_amdgcn_sqrtf(d20) * g), 1e-5f);
      const float te1 = fmaxf(__expf(__builtin_amdgcn_sqrtf(d21) * g), 1e-5f);
      const float te2 = fmaxf(__expf(__builtin_amdgcn_sqrtf(d22) * g), 1e-5f);
      const float te3 = fmaxf(__expf(__builtin_amdgcn_sqrtf(d23) * g), 1e-5f);
      ep0 = __expf(sv0 * te0); ep1 = __expf(sv1 * te1);
      ep2 = __expf(sv2 * te2); ep3 = __expf(sv3 * te3);
      if (diag) {
        ep0 = m0 ? ep0 : 0.f; ep1 = m1 ? ep1 : 0.f;
        ep2 = m2 ? ep2 : 0.f; ep3 = m3 ? ep3 : 0.f;
      }
      z2 += (ep0 + ep1) + (ep2 + ep3);
    }
    const unsigned u0 = cvtpk_bf16(ep0, ep1);
    const unsigned u1 = cvtpk_bf16(ep2, ep3);
    if ((tl & 1) == 0) {
      pk00 = u0; pk01 = u1;
    } else {
      // regroup C-layout P^T (k=hi*4+r) into B-frag (k=hi*8..hi*8+7) over 32 k
      const int srcA = l15 + (((2 * hi) & 3) << 4);
      const int srcB = l15 + (((2 * hi + 1) & 3) << 4);
      unsigned a00 = (unsigned)__shfl((int)pk00, srcA);
      unsigned a01 = (unsigned)__shfl((int)u0,   srcA);
      unsigned a10 = (unsigned)__shfl((int)pk01, srcA);
      unsigned a11 = (unsigned)__shfl((int)u1,   srcA);
      unsigned b00 = (unsigned)__shfl((int)pk00, srcB);
      unsigned b01 = (unsigned)__shfl((int)u0,   srcB);
      unsigned b10 = (unsigned)__shfl((int)pk01, srcB);
      unsigned b11 = (unsigned)__shfl((int)u1,   srcB);
      const bool up = hi >= 2;
      union { unsigned u[4]; bf16x8 v; } pf;
      pf.u[0] = up ? a01 : a00;
      pf.u[1] = up ? a11 : a10;
      pf.u[2] = up ? b01 : b00;
      pf.u[3] = up ? b11 : b10;
      const int jb = (t - 1) * 16;
      bf16x8 vf0 = *(const bf16x8*)(vbase + (size_t)l15 * 1024 + jb + hi * 8);
      bf16x8 vf1 = *(const bf16x8*)(vbase + (size_t)(16 + l15) * 1024 + jb + hi * 8);
      accO0 = __builtin_amdgcn_mfma_f32_16x16x32_bf16(vf0, pf.v, accO0, 0, 0, 0);
      accO1 = __builtin_amdgcn_mfma_f32_16x16x32_bf16(vf1, pf.v, accO1, 0, 0, 0);
    }
    sA_cur = sA_nxt;
  }

  z2 += __shfl_xor(z2, 16);
  z2 += __shfl_xor(z2, 32);
  if (lane < 16) z2buf[w][lane] = z2;
#pragma unroll
  for (int j = 0; j < 4; ++j) {
    accbuf[j][w][lane] = accO0[j];
    accbuf[4 + j][w][lane] = accO1[j];
  }
  __syncthreads();

  if (w == 0) {
    const float z2t = z2buf[0][l15] + z2buf[1][l15] + z2buf[2][l15] + z2buf[3][l15];
    const float inv2 = z2t > 0.f ? 1.f / z2t : 0.f;  // z2t==0: excl row 0 (zero_pad)
    u16* aop = ao + ((size_t)(b * 1024 + i)) * 256 + h * 32;
    float s0[4], s1[4];
#pragma unroll
    for (int j = 0; j < 4; ++j) {
      s0[j] = (accbuf[j][0][lane] + accbuf[j][1][lane] + accbuf[j][2][lane] + accbuf[j][3][lane]) * inv2;
      s1[j] = (accbuf[4 + j][0][lane] + accbuf[4 + j][1][lane] + accbuf[4 + j][2][lane] + accbuf[4 + j][3][lane]) * inv2;
    }
    uint2 o0, o1;
    o0.x = cvtpk_bf16(s0[0], s0[1]); o0.y = cvtpk_bf16(s0[2], s0[3]);
    o1.x = cvtpk_bf16(s1[0], s1[1]); o1.y = cvtpk_bf16(s1[2], s1[3]);
    *(uint2*)(aop + hi * 4) = o0;
    *(uint2*)(aop + 16 + hi * 4) = o1;
  }
}

// ---------------------------------------------------------------------------
__global__ __launch_bounds__(256) void add_ln_kernel(
    const float* __restrict__ res, const float* __restrict__ add,
    const float* __restrict__ g, const float* __restrict__ b,
    float* __restrict__ outf, u16* __restrict__ outb) {
  const int lane = threadIdx.x & 63, wid = threadIdx.x >> 6;
  const size_t row = (size_t)blockIdx.x * 4 + wid;
  const size_t base = row * 256 + lane * 4;
  float4 rv = *(const float4*)(res + base);
  float4 av = *(const float4*)(add + base);
  float x0 = rv.x + av.x, x1 = rv.y + av.y, x2 = rv.z + av.z, x3 = rv.w + av.w;
  float sm = wred_sum(x0 + x1 + x2 + x3);
  float mu = sm * (1.f / 256.f);
  float d0 = x0 - mu, d1 = x1 - mu, d2 = x2 - mu, d3 = x3 - mu;
  float vs = wred_sum(d0 * d0 + d1 * d1 + d2 * d2 + d3 * d3);
  float rs = rsqrtf(vs * (1.f / 256.f) + 1e-5f);
  float4 gv = *(const float4*)(g + lane * 4);
  float4 bv = *(const float4*)(b + lane * 4);
  float o0 = d0 * rs * gv.x + bv.x;
  float o1 = d1 * rs * gv.y + bv.y;
  float o2 = d2 * rs * gv.z + bv.z;
  float o3 = d3 * rs * gv.w + bv.w;
  float4 ov = {o0, o1, o2, o3};
  *(float4*)(outf + base) = ov;
  u16x4 wv; wv[0] = f2bf(o0); wv[1] = f2bf(o1); wv[2] = f2bf(o2); wv[3] = f2bf(o3);
  *(u16x4*)(outb + base) = wv;
}

__global__ __launch_bounds__(256) void cast_bf_kernel(
    const float* __restrict__ in, u16* __restrict__ out) {
  size_t i = ((size_t)blockIdx.x * 256 + threadIdx.x) * 8;
  float4 a = *(const float4*)(in + i);
  float4 c = *(const float4*)(in + i + 4);
  u16x8 o;
  o[0] = f2bf(a.x); o[1] = f2bf(a.y); o[2] = f2bf(a.z); o[3] = f2bf(a.w);
  o[4] = f2bf(c.x); o[5] = f2bf(c.y); o[6] = f2bf(c.z); o[7] = f2bf(c.w);
  *(u16x8*)(out + i) = o;
}

// Wt[z*dstStride + n*K + k] = bf16(W[z*K*N + k*N + n])
__global__ __launch_bounds__(256) void transpose_cast_kernel(
    const float* __restrict__ W, u16* __restrict__ Wt, int K, int N,
    int dstStride) {
  __shared__ float t[32][33];
  const size_t lo = (size_t)blockIdx.z * K * N;
  const size_t lod = (size_t)blockIdx.z * dstStride;
  int n0 = blockIdx.x * 32, k0 = blockIdx.y * 32;
  int tx = threadIdx.x, ty = threadIdx.y;  // 32 x 8
#pragma unroll
  for (int r = 0; r < 32; r += 8)
    t[ty + r][tx] = W[lo + (size_t)(k0 + ty + r) * N + n0 + tx];
  __syncthreads();
#pragma unroll
  for (int r = 0; r < 32; r += 8)
    Wt[lod + (size_t)(n0 + ty + r) * K + k0 + tx] = f2bf(t[tx][ty + r]);
}

// ---------------------------------------------------------------------------
extern "C" void kernel_launch(void* const* d_in, const int* in_sizes, int n_in,
                              void* d_out, int out_size, void* d_ws,
                              size_t ws_size, hipStream_t stream) {
  const float* q_embed = (const float*)d_in[0];
  const float* qa_embed = (const float*)d_in[1];
  const float* Wk = (const float*)d_in[2];
  const float* bk = (const float*)d_in[3];
  const float* Wv = (const float*)d_in[4];
  const float* bv = (const float*)d_in[5];
  const float* Wo = (const float*)d_in[6];
  const float* bo = (const float*)d_in[7];
  const float* gammas = (const float*)d_in[8];
  const float* ln1_g = (const float*)d_in[9];
  const float* ln1_b = (const float*)d_in[10];
  const float* W1 = (const float*)d_in[11];
  const float* b1 = (const float*)d_in[12];
  const float* W2 = (const float*)d_in[13];
  const float* b2 = (const float*)d_in[14];
  const float* ln2_g = (const float*)d_in[15];
  const float* ln2_b = (const float*)d_in[16];

  const size_t ACT_F32 = (size_t)8192 * 256 * 4;  // 8 MB
  const size_t ACT_BF = (size_t)8192 * 256 * 2;   // 4 MB
  char* p = (char*)d_ws;
  auto carve = [&](size_t bytes) {
    void* r = (void*)p;
    p += (bytes + 255) & ~(size_t)255;
    return r;
  };
  float* yb = (float*)carve(ACT_F32);
  float* xb = (float*)carve(ACT_F32);
  float* pof = (float*)carve(ACT_F32);
  u16* xbf = (u16*)carve(ACT_BF);
  u16* ybf = (u16*)carve(ACT_BF);
  u16* qkbf = (u16*)carve(ACT_BF);
  u16* vTb = (u16*)carve(ACT_BF);
  u16* aobf = (u16*)carve(ACT_BF);
  u16* hbf = (u16*)carve((size_t)8192 * 1024 * 2);  // 16 MB
  u16* Wkvt = (u16*)carve((size_t)3 * 131072 * 2);
  u16* Wot = (u16*)carve((size_t)3 * 65536 * 2);
  u16* W1t = (u16*)carve((size_t)3 * 262144 * 2);
  u16* W2t = (u16*)carve((size_t)3 * 262144 * 2);

  dim3 tb(32, 8);
  transpose_cast_kernel<<<dim3(8, 8, 3), tb, 0, stream>>>(Wk, Wkvt, 256, 256, 131072);
  transpose_cast_kernel<<<dim3(8, 8, 3), tb, 0, stream>>>(Wv, Wkvt + 65536, 256, 256, 131072);
  transpose_cast_kernel<<<dim3(8, 8, 3), tb, 0, stream>>>(Wo, Wot, 256, 256, 65536);
  transpose_cast_kernel<<<dim3(32, 8, 3), tb, 0, stream>>>(W1, W1t, 256, 1024, 262144);
  transpose_cast_kernel<<<dim3(8, 32, 3), tb, 0, stream>>>(W2, W2t, 1024, 256, 262144);
  cast_bf_kernel<<<1024, 256, 0, stream>>>(q_embed, xbf);
  cast_bf_kernel<<<1024, 256, 0, stream>>>(qa_embed, ybf);

  const dim3 gP(128, 4), gF(128, 16), gKV(128, 8);
  const dim3 gA(64, 64);

  // ---- block 0: layer 0, y = qa, incl mask, FFN ----
  gemm_kv_kernel<<<gKV, 256, 0, stream>>>(ybf, Wkvt, bk, bv, qkbf, vTb, 8192, 512, 256);
  attn_mfma_kernel<<<gA, 256, 0, stream>>>(qkbf, vTb, aobf, gammas, 0);
  gemm_kernel<0, 1, 0, 0><<<gP, 256, 0, stream>>>(aobf, Wot, bo, pof, nullptr, 8192, 256, 256);
  add_ln_kernel<<<2048, 256, 0, stream>>>(qa_embed, pof, ln1_g, ln1_b, yb, ybf);
  gemm_kernel<1, 0, 1, 0><<<gF, 256, 0, stream>>>(ybf, W1t, b1, nullptr, hbf, 8192, 1024, 256);
  gemm_kernel<0, 1, 0, 0><<<gP, 256, 0, stream>>>(hbf, W2t, b2, pof, nullptr, 8192, 256, 1024);
  add_ln_kernel<<<2048, 256, 0, stream>>>(yb, pof, ln2_g, ln2_b, yb, ybf);

  // ---- block 1: layer 1, x = q_embed, incl mask, no FFN ----
  gemm_kv_kernel<<<gKV, 256, 0, stream>>>(xbf, Wkvt + 131072, bk + 256, bv + 256, qkbf, vTb, 8192, 512, 256);
  attn_mfma_kernel<<<gA, 256, 0, stream>>>(qkbf, vTb, aobf, gammas + 8, 0);
  gemm_kernel<0, 1, 0, 0><<<gP, 256, 0, stream>>>(aobf, Wot + 65536, bo + 256, pof, nullptr, 8192, 256, 256);
  add_ln_kernel<<<2048, 256, 0, stream>>>(q_embed, pof, ln1_g + 256, ln1_b + 256, xb, xbf);

  // ---- block 2: layer 2, q/k from x, v from y, excl mask (zero_pad natural) ----
  // Fused KV writes V(x) into vTb (garbage), then the V(y) GEMM fully
  // overwrites vTb before attention reads it (same stream => ordered).
  gemm_kv_kernel<<<gKV, 256, 0, stream>>>(xbf, Wkvt + 262144, bk + 512, bv + 512, qkbf, vTb, 8192, 512, 256);
  gemm_kernel<0, 0, 0, 1><<<gP, 256, 0, stream>>>(ybf, Wkvt + 262144 + 65536, bv + 512, nullptr, vTb, 8192, 256, 256);
  attn_mfma_kernel<<<gA, 256, 0, stream>>>(qkbf, vTb, aobf, gammas + 16, 1);
  gemm_kernel<0, 1, 0, 0><<<gP, 256, 0, stream>>>(aobf, Wot + 131072, bo + 512, pof, nullptr, 8192, 256, 256);
  add_ln_kernel<<<2048, 256, 0, stream>>>(xb, pof, ln1_g + 512, ln1_b + 512, xb, xbf);
  gemm_kernel<1, 0, 1, 0><<<gF, 256, 0, stream>>>(xbf, W1t + 524288, b1 + 2048, nullptr, hbf, 8192, 1024, 256);
  gemm_kernel<0, 1, 0, 0><<<gP, 256, 0, stream>>>(hbf, W2t + 524288, b2 + 512, pof, nullptr, 8192, 256, 1024);
  add_ln_kernel<<<2048, 256, 0, stream>>>(xb, pof, ln2_g + 512, ln2_b + 512, (float*)d_out, xbf);
}

// Round 7
// 298.341 us; speedup vs baseline: 5.4841x; 1.0231x over previous
//
#include <hip/hip_runtime.h>

typedef unsigned short u16;
typedef float f32x4 __attribute__((ext_vector_type(4)));
typedef __bf16 bf16x8 __attribute__((ext_vector_type(8)));
typedef u16 u16x8 __attribute__((ext_vector_type(8)));
typedef u16 u16x4 __attribute__((ext_vector_type(4)));
typedef __fp16 h16x2 __attribute__((ext_vector_type(2)));

__device__ __forceinline__ u16 f2bf(float f) {
  union { float f; unsigned u; } v; v.f = f;
  unsigned r = (v.u + 0x7FFFu + ((v.u >> 16) & 1u)) >> 16;
  return (u16)r;
}
__device__ __forceinline__ unsigned cvtpk_bf16(float lo, float hi) {
  unsigned r;
  asm("v_cvt_pk_bf16_f32 %0, %1, %2" : "=v"(r) : "v"(lo), "v"(hi));
  return r;
}
__device__ __forceinline__ unsigned pk_f16(float a, float b) {
  union { h16x2 h; unsigned u; } v;
  v.h = __builtin_amdgcn_cvt_pkrtz(a, b);
  return v.u;
}
__device__ __forceinline__ float2 unpk_f16(unsigned u) {
  union { unsigned u; h16x2 h; } v; v.u = u;
  return make_float2((float)v.h.x, (float)v.h.y);
}
__device__ __forceinline__ float wred_sum(float v) {
#pragma unroll
  for (int o = 32; o >= 1; o >>= 1) v += __shfl_xor(v, o);
  return v;
}

// ---------------------------------------------------------------------------
// bf16 MFMA GEMM: C = A[M,K] @ Bt[N,K]^T + bias. Outputs:
//  WF32: f32 [M][N];  WBF: bf16 [M][N];  WVT: bf16 head-transposed [bh][d][s]
// ---------------------------------------------------------------------------
template <int RELU, int WF32, int WBF, int WVT>
__global__ __launch_bounds__(256) void gemm_kernel(
    const u16* __restrict__ A, const u16* __restrict__ Bt,
    const float* __restrict__ bias, float* __restrict__ C,
    u16* __restrict__ Cbf, int M, int N, int K) {
  __shared__ u16 As[64 * 64];
  __shared__ u16 Bs[64 * 64];
  const int tid = threadIdx.x;
  const int lane = tid & 63;
  const int w = tid >> 6;
  const int m0 = blockIdx.x * 64;
  const int n0 = blockIdx.y * 64;
  const int wr = (w >> 1) * 32;
  const int wc = (w & 1) * 32;
  const int l15 = lane & 15, hi = lane >> 4;

  f32x4 acc[2][2] = {};

  for (int k0 = 0; k0 < K; k0 += 64) {
#pragma unroll
    for (int rep = 0; rep < 2; ++rep) {
      int idx = tid + rep * 256;
      int row = idx >> 3, c8 = idx & 7;
      int cs = ((c8 ^ (row & 7)) << 3);
      __builtin_amdgcn_global_load_lds(
          (const __attribute__((address_space(1))) void*)(A + (size_t)(m0 + row) * K + k0 + cs),
          (__attribute__((address_space(3))) void*)(&As[idx * 8]), 16, 0, 0);
      __builtin_amdgcn_global_load_lds(
          (const __attribute__((address_space(1))) void*)(Bt + (size_t)(n0 + row) * K + k0 + cs),
          (__attribute__((address_space(3))) void*)(&Bs[idx * 8]), 16, 0, 0);
    }
    __syncthreads();
#pragma unroll
    for (int kk = 0; kk < 2; ++kk) {
      int kb = (kk * 32 + (hi << 3)) << 1;
      bf16x8 af[2], bfr[2];
#pragma unroll
      for (int mf = 0; mf < 2; ++mf) {
        int m = wr + mf * 16 + l15;
        af[mf] = *(const bf16x8*)((const char*)As + m * 128 + (kb ^ ((m & 7) << 4)));
      }
#pragma unroll
      for (int nf = 0; nf < 2; ++nf) {
        int n = wc + nf * 16 + l15;
        bfr[nf] = *(const bf16x8*)((const char*)Bs + n * 128 + (kb ^ ((n & 7) << 4)));
      }
#pragma unroll
      for (int mf = 0; mf < 2; ++mf)
#pragma unroll
        for (int nf = 0; nf < 2; ++nf)
          acc[mf][nf] = __builtin_amdgcn_mfma_f32_16x16x32_bf16(af[mf], bfr[nf], acc[mf][nf], 0, 0, 0);
    }
    __syncthreads();
  }

#pragma unroll
  for (int mf = 0; mf < 2; ++mf)
#pragma unroll
    for (int nf = 0; nf < 2; ++nf) {
      int col = n0 + wc + nf * 16 + l15;
      float bia = bias[col];
      u16x4 tv;
#pragma unroll
      for (int r = 0; r < 4; ++r) {
        int row = m0 + wr + mf * 16 + (hi << 2) + r;
        float val = acc[mf][nf][r] + bia;
        if (RELU) val = fmaxf(val, 0.f);
        if (WF32) C[(size_t)row * N + col] = val;
        if (WBF) Cbf[(size_t)row * N + col] = f2bf(val);
        if (WVT) tv[r] = f2bf(val);
      }
      if (WVT) {
        int row0 = m0 + wr + mf * 16 + (hi << 2);
        size_t addr = (((size_t)(row0 >> 10) * 8 + (col >> 5)) * 32 + (col & 31)) * 1024 + (row0 & 1023);
        *(u16x4*)(Cbf + addr) = tv;
      }
    }
}

// ---------------------------------------------------------------------------
// Fused K+V projection: A[8192,256] @ WkvT[512,256]^T. Cols 0..255 -> qkbf
// (bf16 row-major, bias bk); cols 256..511 -> vT scatter (bias bv).
// vT must be a valid pointer (V half is always written).
// ---------------------------------------------------------------------------
__global__ __launch_bounds__(256) void gemm_kv_kernel(
    const u16* __restrict__ A, const u16* __restrict__ Bt,
    const float* __restrict__ biasK, const float* __restrict__ biasV,
    u16* __restrict__ qkbf, u16* __restrict__ vT, int M, int N, int K) {
  __shared__ u16 As[64 * 64];
  __shared__ u16 Bs[64 * 64];
  const int tid = threadIdx.x;
  const int lane = tid & 63;
  const int w = tid >> 6;
  const int m0 = blockIdx.x * 64;
  const int n0 = blockIdx.y * 64;
  const int wr = (w >> 1) * 32;
  const int wc = (w & 1) * 32;
  const int l15 = lane & 15, hi = lane >> 4;

  f32x4 acc[2][2] = {};

  for (int k0 = 0; k0 < K; k0 += 64) {
#pragma unroll
    for (int rep = 0; rep < 2; ++rep) {
      int idx = tid + rep * 256;
      int row = idx >> 3, c8 = idx & 7;
      int cs = ((c8 ^ (row & 7)) << 3);
      __builtin_amdgcn_global_load_lds(
          (const __attribute__((address_space(1))) void*)(A + (size_t)(m0 + row) * K + k0 + cs),
          (__attribute__((address_space(3))) void*)(&As[idx * 8]), 16, 0, 0);
      __builtin_amdgcn_global_load_lds(
          (const __attribute__((address_space(1))) void*)(Bt + (size_t)(n0 + row) * K + k0 + cs),
          (__attribute__((address_space(3))) void*)(&Bs[idx * 8]), 16, 0, 0);
    }
    __syncthreads();
#pragma unroll
    for (int kk = 0; kk < 2; ++kk) {
      int kb = (kk * 32 + (hi << 3)) << 1;
      bf16x8 af[2], bfr[2];
#pragma unroll
      for (int mf = 0; mf < 2; ++mf) {
        int m = wr + mf * 16 + l15;
        af[mf] = *(const bf16x8*)((const char*)As + m * 128 + (kb ^ ((m & 7) << 4)));
      }
#pragma unroll
      for (int nf = 0; nf < 2; ++nf) {
        int n = wc + nf * 16 + l15;
        bfr[nf] = *(const bf16x8*)((const char*)Bs + n * 128 + (kb ^ ((n & 7) << 4)));
      }
#pragma unroll
      for (int mf = 0; mf < 2; ++mf)
#pragma unroll
        for (int nf = 0; nf < 2; ++nf)
          acc[mf][nf] = __builtin_amdgcn_mfma_f32_16x16x32_bf16(af[mf], bfr[nf], acc[mf][nf], 0, 0, 0);
    }
    __syncthreads();
  }

  const bool isV = (n0 >= 256);
#pragma unroll
  for (int mf = 0; mf < 2; ++mf)
#pragma unroll
    for (int nf = 0; nf < 2; ++nf) {
      int col = n0 + wc + nf * 16 + l15;
      float bia = isV ? biasV[col - 256] : biasK[col];
      u16x4 tv;
#pragma unroll
      for (int r = 0; r < 4; ++r) {
        int row = m0 + wr + mf * 16 + (hi << 2) + r;
        float val = acc[mf][nf][r] + bia;
        if (!isV) qkbf[(size_t)row * 256 + col] = f2bf(val);
        tv[r] = f2bf(val);
      }
      if (isV) {
        int row0 = m0 + wr + mf * 16 + (hi << 2);
        int vc = col - 256;
        size_t addr = (((size_t)(row0 >> 10) * 8 + (vc >> 5)) * 32 + (vc & 31)) * 1024 + (row0 & 1023);
        *(u16x4*)(vT + addr) = tv;
      }
    }
}

// ---------------------------------------------------------------------------
// MFMA distance-decay attention, k-chunked across the block's 4 waves.
// Pass A computes log2-domain scores l = s*scale*log2e once (QK MFMA),
// packs them to f16x2 in registers (<=16 tiles -> 32 VGPRs) and accumulates
// chunk-partial Z. Pass B is load/MFMA-free softmax+decay from the cached l:
// e = v_exp(l), P = v_exp(l*te). Masked elements store l=-1000 so the whole
// decay chain yields P=0 automatically (pos<=0 -> d2=0 -> te=1 -> 2^-1000=0).
// ---------------------------------------------------------------------------
__global__ __launch_bounds__(256) void attn_mfma_kernel(
    const u16* __restrict__ qkbf, const u16* __restrict__ vT,
    u16* __restrict__ ao, const float* __restrict__ gam, int excl) {
  __shared__ float zbuf[4][16];
  __shared__ float z2buf[4][16];
  __shared__ float accbuf[8][4][64];

  const int lane = threadIdx.x & 63, w = threadIdx.x >> 6;
  const int qt = 63 - blockIdx.y;  // big-work blocks dispatch first
  const int bh = blockIdx.x;
  const int b = bh >> 3, h = bh & 7;
  const int q0 = qt * 16;
  const int l15 = lane & 15, hi = lane >> 4;
  const int i = q0 + l15;  // this lane's q row
  const float LOG2E = 1.4426950408889634f;
  const float g2 = -log1pf(__expf(gam[h])) * LOG2E;      // g in log2 domain
  const float cscale = 0.17677669529663687f * LOG2E;     // 1/sqrt(32)*log2e
  const float CLIP2 = -16.609640474436812f;              // log2(1e-5)

  const u16* kbase = qkbf + ((size_t)b * 1024) * 256 + h * 32;
  const bf16x8 qfrag = *(const bf16x8*)(kbase + (size_t)i * 256 + hi * 8);

  const int mylim = i - excl;            // valid k <= mylim
  const int jmax = q0 + 15 - excl;       // block-wide max valid k
  const int ntiles = (jmax >> 4) + 1;
  const int C = (ntiles + 3) >> 2;       // tiles per wave chunk (<=16)
  const int c0 = w * C;
  const int tEnd = (c0 + C < ntiles) ? (c0 + C) : ntiles;
  const int count = (tEnd > c0) ? (tEnd - c0) : 0;

  // ---- pass A: QK MFMA once, cache l (f16x2), chunk-partial Z ----
  unsigned lpk[32];                      // [tile][2]: (l0,l1),(l2,l3)
  float zacc = 0.f;
#pragma unroll
  for (int tl = 0; tl < 16; ++tl) {
    if (tl < count) {                    // wave-uniform
      const int t = c0 + tl;
      bf16x8 kf = *(const bf16x8*)(kbase + (size_t)(t * 16 + l15) * 256 + hi * 8);
      f32x4 sA = {};
      sA = __builtin_amdgcn_mfma_f32_16x16x32_bf16(kf, qfrag, sA, 0, 0, 0);
      float l0 = sA[0] * cscale, l1 = sA[1] * cscale;
      float l2 = sA[2] * cscale, l3 = sA[3] * cscale;
      if (t == ntiles - 1) {             // wave-uniform diagonal tile
        const int kb = t * 16 + hi * 4;
        l0 = (kb + 0 <= mylim) ? l0 : -1000.f;
        l1 = (kb + 1 <= mylim) ? l1 : -1000.f;
        l2 = (kb + 2 <= mylim) ? l2 : -1000.f;
        l3 = (kb + 3 <= mylim) ? l3 : -1000.f;
      }
      zacc += (exp2f(l0) + exp2f(l1)) + (exp2f(l2) + exp2f(l3));
      lpk[2 * tl] = pk_f16(l0, l1);
      lpk[2 * tl + 1] = pk_f16(l2, l3);
    } else {
      lpk[2 * tl] = 0xE3D0E3D0u;         // f16(-1000) pair
      lpk[2 * tl + 1] = 0xE3D0E3D0u;
    }
  }
  zacc += __shfl_xor(zacc, 16);
  zacc += __shfl_xor(zacc, 32);          // per-row chunk sum, replicated
  if (lane < 16) zbuf[w][lane] = zacc;
  __syncthreads();

  const float zc0 = zbuf[0][l15], zc1 = zbuf[1][l15];
  const float zc2 = zbuf[2][l15], zc3 = zbuf[3][l15];
  const float Z = zc0 + zc1 + zc2 + zc3;
  const float invZ = Z > 0.f ? 1.f / Z : 0.f;
  float prefix = 0.f;
  if (w > 0) prefix += zc0;
  if (w > 1) prefix += zc1;
  if (w > 2) prefix += zc2;

  // ---- pass B: load-free cumsum -> decay -> softmax2 -> PV ----
  const u16* vbase = vT + (size_t)bh * 32 * 1024;
  float carry = prefix, z2 = 0.f;
  f32x4 accO0 = {}, accO1 = {};
  const int Cp = (count + 1) & ~1;

  auto tile_sm = [&](int tlocal, unsigned pa, unsigned pb,
                     unsigned& u0, unsigned& u1) {
    float2 v01 = unpk_f16(pa), v23 = unpk_f16(pb);
    const float l0 = v01.x, l1 = v01.y, l2 = v23.x, l3 = v23.y;
    const float e0 = exp2f(l0), e1 = exp2f(l1);
    const float e2 = exp2f(l2), e3 = exp2f(l3);
    const float cA = e0 + e1, cB = cA + e2, cC = cB + e3;
    float vsc = cC;
    float tmp = __shfl_up(vsc, 16); if (hi >= 1) vsc += tmp;
    tmp = __shfl_up(vsc, 32); if (hi >= 2) vsc += tmp;
    const float exg = vsc - cC;
    const float tot = __shfl(vsc, l15 + 48);
    const float cb = carry + exg;
    carry += tot;
    const int kb = (c0 + tlocal) * 16 + hi * 4;
    const float posb = (float)(i - kb);
    const float r0 = (Z - (cb + e0)) * invZ;
    const float r1 = (Z - (cb + cA)) * invZ;
    const float r2 = (Z - (cb + cB)) * invZ;
    const float r3 = (Z - (cb + cC)) * invZ;
    const float d20 = fmaxf(r0 * posb, 0.f);
    const float d21 = fmaxf(r1 * (posb - 1.f), 0.f);
    const float d22 = fmaxf(r2 * (posb - 2.f), 0.f);
    const float d23 = fmaxf(r3 * (posb - 3.f), 0.f);
    const float a0 = fmaxf(__builtin_amdgcn_sqrtf(d20) * g2, CLIP2);
    const float a1 = fmaxf(__builtin_amdgcn_sqrtf(d21) * g2, CLIP2);
    const float a2 = fmaxf(__builtin_amdgcn_sqrtf(d22) * g2, CLIP2);
    const float a3 = fmaxf(__builtin_amdgcn_sqrtf(d23) * g2, CLIP2);
    const float p0 = exp2f(l0 * exp2f(a0));
    const float p1 = exp2f(l1 * exp2f(a1));
    const float p2 = exp2f(l2 * exp2f(a2));
    const float p3 = exp2f(l3 * exp2f(a3));
    z2 += (p0 + p1) + (p2 + p3);
    u0 = cvtpk_bf16(p0, p1);
    u1 = cvtpk_bf16(p2, p3);
  };

#pragma unroll
  for (int pp = 0; pp < 8; ++pp) {
    if (2 * pp < Cp) {                   // wave-uniform
      unsigned pk00, pk01, u0, u1;
      tile_sm(2 * pp, lpk[4 * pp], lpk[4 * pp + 1], pk00, pk01);
      tile_sm(2 * pp + 1, lpk[4 * pp + 2], lpk[4 * pp + 3], u0, u1);
      // regroup C-layout P^T (k=hi*4+r) into B-frag (k=hi*8..hi*8+7) over 32 k
      const int srcA = l15 + (((2 * hi) & 3) << 4);
      const int srcB = l15 + (((2 * hi + 1) & 3) << 4);
      unsigned a00 = (unsigned)__shfl((int)pk00, srcA);
      unsigned a01 = (unsigned)__shfl((int)u0,   srcA);
      unsigned a10 = (unsigned)__shfl((int)pk01, srcA);
      unsigned a11 = (unsigned)__shfl((int)u1,   srcA);
      unsigned b00 = (unsigned)__shfl((int)pk00, srcB);
      unsigned b01 = (unsigned)__shfl((int)u0,   srcB);
      unsigned b10 = (unsigned)__shfl((int)pk01, srcB);
      unsigned b11 = (unsigned)__shfl((int)u1,   srcB);
      const bool up = hi >= 2;
      union { unsigned u[4]; bf16x8 v; } pf;
      pf.u[0] = up ? a01 : a00;
      pf.u[1] = up ? a11 : a10;
      pf.u[2] = up ? b01 : b00;
      pf.u[3] = up ? b11 : b10;
      const int jb = (c0 + 2 * pp) * 16;
      bf16x8 vf0 = *(const bf16x8*)(vbase + (size_t)l15 * 1024 + jb + hi * 8);
      bf16x8 vf1 = *(const bf16x8*)(vbase + (size_t)(16 + l15) * 1024 + jb + hi * 8);
      accO0 = __builtin_amdgcn_mfma_f32_16x16x32_bf16(vf0, pf.v, accO0, 0, 0, 0);
      accO1 = __builtin_amdgcn_mfma_f32_16x16x32_bf16(vf1, pf.v, accO1, 0, 0, 0);
    }
  }

  z2 += __shfl_xor(z2, 16);
  z2 += __shfl_xor(z2, 32);
  if (lane < 16) z2buf[w][lane] = z2;
#pragma unroll
  for (int j = 0; j < 4; ++j) {
    accbuf[j][w][lane] = accO0[j];
    accbuf[4 + j][w][lane] = accO1[j];
  }
  __syncthreads();

  if (w == 0) {
    const float z2t = z2buf[0][l15] + z2buf[1][l15] + z2buf[2][l15] + z2buf[3][l15];
    const float inv2 = z2t > 0.f ? 1.f / z2t : 0.f;  // z2t==0: excl row 0 (zero_pad)
    u16* aop = ao + ((size_t)(b * 1024 + i)) * 256 + h * 32;
    float s0[4], s1[4];
#pragma unroll
    for (int j = 0; j < 4; ++j) {
      s0[j] = (accbuf[j][0][lane] + accbuf[j][1][lane] + accbuf[j][2][lane] + accbuf[j][3][lane]) * inv2;
      s1[j] = (accbuf[4 + j][0][lane] + accbuf[4 + j][1][lane] + accbuf[4 + j][2][lane] + accbuf[4 + j][3][lane]) * inv2;
    }
    uint2 o0, o1;
    o0.x = cvtpk_bf16(s0[0], s0[1]); o0.y = cvtpk_bf16(s0[2], s0[3]);
    o1.x = cvtpk_bf16(s1[0], s1[1]); o1.y = cvtpk_bf16(s1[2], s1[3]);
    *(uint2*)(aop + hi * 4) = o0;
    *(uint2*)(aop + 16 + hi * 4) = o1;
  }
}

// ---------------------------------------------------------------------------
__global__ __launch_bounds__(256) void add_ln_kernel(
    const float* __restrict__ res, const float* __restrict__ add,
    const float* __restrict__ g, const float* __restrict__ b,
    float* __restrict__ outf, u16* __restrict__ outb) {
  const int lane = threadIdx.x & 63, wid = threadIdx.x >> 6;
  const size_t row = (size_t)blockIdx.x * 4 + wid;
  const size_t base = row * 256 + lane * 4;
  float4 rv = *(const float4*)(res + base);
  float4 av = *(const float4*)(add + base);
  float x0 = rv.x + av.x, x1 = rv.y + av.y, x2 = rv.z + av.z, x3 = rv.w + av.w;
  float sm = wred_sum(x0 + x1 + x2 + x3);
  float mu = sm * (1.f / 256.f);
  float d0 = x0 - mu, d1 = x1 - mu, d2 = x2 - mu, d3 = x3 - mu;
  float vs = wred_sum(d0 * d0 + d1 * d1 + d2 * d2 + d3 * d3);
  float rs = rsqrtf(vs * (1.f / 256.f) + 1e-5f);
  float4 gv = *(const float4*)(g + lane * 4);
  float4 bv = *(const float4*)(b + lane * 4);
  float o0 = d0 * rs * gv.x + bv.x;
  float o1 = d1 * rs * gv.y + bv.y;
  float o2 = d2 * rs * gv.z + bv.z;
  float o3 = d3 * rs * gv.w + bv.w;
  float4 ov = {o0, o1, o2, o3};
  *(float4*)(outf + base) = ov;
  u16x4 wv; wv[0] = f2bf(o0); wv[1] = f2bf(o1); wv[2] = f2bf(o2); wv[3] = f2bf(o3);
  *(u16x4*)(outb + base) = wv;
}

__global__ __launch_bounds__(256) void cast_bf_kernel(
    const float* __restrict__ in, u16* __restrict__ out) {
  size_t i = ((size_t)blockIdx.x * 256 + threadIdx.x) * 8;
  float4 a = *(const float4*)(in + i);
  float4 c = *(const float4*)(in + i + 4);
  u16x8 o;
  o[0] = f2bf(a.x); o[1] = f2bf(a.y); o[2] = f2bf(a.z); o[3] = f2bf(a.w);
  o[4] = f2bf(c.x); o[5] = f2bf(c.y); o[6] = f2bf(c.z); o[7] = f2bf(c.w);
  *(u16x8*)(out + i) = o;
}

// Wt[z*dstStride + n*K + k] = bf16(W[z*K*N + k*N + n])
__global__ __launch_bounds__(256) void transpose_cast_kernel(
    const float* __restrict__ W, u16* __restrict__ Wt, int K, int N,
    int dstStride) {
  __shared__ float t[32][33];
  const size_t lo = (size_t)blockIdx.z * K * N;
  const size_t lod = (size_t)blockIdx.z * dstStride;
  int n0 = blockIdx.x * 32, k0 = blockIdx.y * 32;
  int tx = threadIdx.x, ty = threadIdx.y;  // 32 x 8
#pragma unroll
  for (int r = 0; r < 32; r += 8)
    t[ty + r][tx] = W[lo + (size_t)(k0 + ty + r) * N + n0 + tx];
  __syncthreads();
#pragma unroll
  for (int r = 0; r < 32; r += 8)
    Wt[lod + (size_t)(n0 + ty + r) * K + k0 + tx] = f2bf(t[tx][ty + r]);
}

// ---------------------------------------------------------------------------
extern "C" void kernel_launch(void* const* d_in, const int* in_sizes, int n_in,
                              void* d_out, int out_size, void* d_ws,
                              size_t ws_size, hipStream_t stream) {
  const float* q_embed = (const float*)d_in[0];
  const float* qa_embed = (const float*)d_in[1];
  const float* Wk = (const float*)d_in[2];
  const float* bk = (const float*)d_in[3];
  const float* Wv = (const float*)d_in[4];
  const float* bv = (const float*)d_in[5];
  const float* Wo = (const float*)d_in[6];
  const float* bo = (const float*)d_in[7];
  const float* gammas = (const float*)d_in[8];
  const float* ln1_g = (const float*)d_in[9];
  const float* ln1_b = (const float*)d_in[10];
  const float* W1 = (const float*)d_in[11];
  const float* b1 = (const float*)d_in[12];
  const float* W2 = (const float*)d_in[13];
  const float* b2 = (const float*)d_in[14];
  const float* ln2_g = (const float*)d_in[15];
  const float* ln2_b = (const float*)d_in[16];

  const size_t ACT_F32 = (size_t)8192 * 256 * 4;  // 8 MB
  const size_t ACT_BF = (size_t)8192 * 256 * 2;   // 4 MB
  char* p = (char*)d_ws;
  auto carve = [&](size_t bytes) {
    void* r = (void*)p;
    p += (bytes + 255) & ~(size_t)255;
    return r;
  };
  float* yb = (float*)carve(ACT_F32);
  float* xb = (float*)carve(ACT_F32);
  float* pof = (float*)carve(ACT_F32);
  u16* xbf = (u16*)carve(ACT_BF);
  u16* ybf = (u16*)carve(ACT_BF);
  u16* qkbf = (u16*)carve(ACT_BF);
  u16* vTb = (u16*)carve(ACT_BF);
  u16* aobf = (u16*)carve(ACT_BF);
  u16* hbf = (u16*)carve((size_t)8192 * 1024 * 2);  // 16 MB
  u16* Wkvt = (u16*)carve((size_t)3 * 131072 * 2);
  u16* Wot = (u16*)carve((size_t)3 * 65536 * 2);
  u16* W1t = (u16*)carve((size_t)3 * 262144 * 2);
  u16* W2t = (u16*)carve((size_t)3 * 262144 * 2);

  dim3 tb(32, 8);
  transpose_cast_kernel<<<dim3(8, 8, 3), tb, 0, stream>>>(Wk, Wkvt, 256, 256, 131072);
  transpose_cast_kernel<<<dim3(8, 8, 3), tb, 0, stream>>>(Wv, Wkvt + 65536, 256, 256, 131072);
  transpose_cast_kernel<<<dim3(8, 8, 3), tb, 0, stream>>>(Wo, Wot, 256, 256, 65536);
  transpose_cast_kernel<<<dim3(32, 8, 3), tb, 0, stream>>>(W1, W1t, 256, 1024, 262144);
  transpose_cast_kernel<<<dim3(8, 32, 3), tb, 0, stream>>>(W2, W2t, 1024, 256, 262144);
  cast_bf_kernel<<<1024, 256, 0, stream>>>(q_embed, xbf);
  cast_bf_kernel<<<1024, 256, 0, stream>>>(qa_embed, ybf);

  const dim3 gP(128, 4), gF(128, 16), gKV(128, 8);
  const dim3 gA(64, 64);

  // ---- block 0: layer 0, y = qa, incl mask, FFN ----
  gemm_kv_kernel<<<gKV, 256, 0, stream>>>(ybf, Wkvt, bk, bv, qkbf, vTb, 8192, 512, 256);
  attn_mfma_kernel<<<gA, 256, 0, stream>>>(qkbf, vTb, aobf, gammas, 0);
  gemm_kernel<0, 1, 0, 0><<<gP, 256, 0, stream>>>(aobf, Wot, bo, pof, nullptr, 8192, 256, 256);
  add_ln_kernel<<<2048, 256, 0, stream>>>(qa_embed, pof, ln1_g, ln1_b, yb, ybf);
  gemm_kernel<1, 0, 1, 0><<<gF, 256, 0, stream>>>(ybf, W1t, b1, nullptr, hbf, 8192, 1024, 256);
  gemm_kernel<0, 1, 0, 0><<<gP, 256, 0, stream>>>(hbf, W2t, b2, pof, nullptr, 8192, 256, 1024);
  add_ln_kernel<<<2048, 256, 0, stream>>>(yb, pof, ln2_g, ln2_b, yb, ybf);

  // ---- block 1: layer 1, x = q_embed, incl mask, no FFN ----
  gemm_kv_kernel<<<gKV, 256, 0, stream>>>(xbf, Wkvt + 131072, bk + 256, bv + 256, qkbf, vTb, 8192, 512, 256);
  attn_mfma_kernel<<<gA, 256, 0, stream>>>(qkbf, vTb, aobf, gammas + 8, 0);
  gemm_kernel<0, 1, 0, 0><<<gP, 256, 0, stream>>>(aobf, Wot + 65536, bo + 256, pof, nullptr, 8192, 256, 256);
  add_ln_kernel<<<2048, 256, 0, stream>>>(q_embed, pof, ln1_g + 256, ln1_b + 256, xb, xbf);

  // ---- block 2: layer 2, q/k from x, v from y, excl mask (zero_pad natural) ----
  // Fused KV writes V(x) into vTb (garbage), then the V(y) GEMM fully
  // overwrites vTb before attention reads it (same stream => ordered).
  gemm_kv_kernel<<<gKV, 256, 0, stream>>>(xbf, Wkvt + 262144, bk + 512, bv + 512, qkbf, vTb, 8192, 512, 256);
  gemm_kernel<0, 0, 0, 1><<<gP, 256, 0, stream>>>(ybf, Wkvt + 262144 + 65536, bv + 512, nullptr, vTb, 8192, 256, 256);
  attn_mfma_kernel<<<gA, 256, 0, stream>>>(qkbf, vTb, aobf, gammas + 16, 1);
  gemm_kernel<0, 1, 0, 0><<<gP, 256, 0, stream>>>(aobf, Wot + 131072, bo + 512, pof, nullptr, 8192, 256, 256);
  add_ln_kernel<<<2048, 256, 0, stream>>>(xb, pof, ln1_g + 512, ln1_b + 512, xb, xbf);
  gemm_kernel<1, 0, 1, 0><<<gF, 256, 0, stream>>>(xbf, W1t + 524288, b1 + 2048, nullptr, hbf, 8192, 1024, 256);
  gemm_kernel<0, 1, 0, 0><<<gP, 256, 0, stream>>>(hbf, W2t + 524288, b2 + 512, pof, nullptr, 8192, 256, 1024);
  add_ln_kernel<<<2048, 256, 0, stream>>>(xb, pof, ln2_g + 512, ln2_b + 512, (float*)d_out, xbf);
}